// Round 1
// baseline (1028.857 us; speedup 1.0000x reference)
//
#include <hip/hip_runtime.h>
#include <hip/hip_bf16.h>
#include <math.h>

// Problem constants (match reference)
#define N_NODES 50000
#define N_EDGES 1600000
#define NFEAT 512
#define NHID 128
#define NCLASS 40

// ---------------- CSR build ----------------

__global__ __launch_bounds__(256) void zero_counts(int* counts, int n) {
    int i = blockIdx.x * 256 + threadIdx.x;
    if (i < n) counts[i] = 0;
}

__global__ __launch_bounds__(256) void hist_kernel(const int* __restrict__ dst,
                                                   int* __restrict__ counts, int n) {
    int e = blockIdx.x * 256 + threadIdx.x;
    if (e < n) atomicAdd(&counts[dst[e]], 1);
}

// Single-block exclusive scan over n counts -> row_ptr[0..n], cursor copy.
__global__ __launch_bounds__(1024) void scan_kernel(const int* __restrict__ counts,
                                                    int* __restrict__ row_ptr,
                                                    int* __restrict__ cursor, int n) {
    __shared__ int sums[1024];
    const int tid = threadIdx.x;
    const int chunk = (n + 1023) / 1024;
    const int start = tid * chunk;
    const int end = min(start + chunk, n);
    int s = 0;
    for (int i = start; i < end; ++i) s += counts[i];
    sums[tid] = s;
    __syncthreads();
    // Hillis-Steele inclusive scan
    for (int off = 1; off < 1024; off <<= 1) {
        int v = (tid >= off) ? sums[tid - off] : 0;
        __syncthreads();
        sums[tid] += v;
        __syncthreads();
    }
    int prev = (tid == 0) ? 0 : sums[tid - 1];
    int run = prev;
    for (int i = start; i < end; ++i) {
        row_ptr[i] = run;
        cursor[i] = run;
        run += counts[i];
    }
    if (end == n) row_ptr[n] = run;  // all trailing threads write same total
}

__global__ __launch_bounds__(256) void scatter_kernel(const int* __restrict__ src,
                                                      const int* __restrict__ dst,
                                                      const float* __restrict__ w,
                                                      int* __restrict__ cursor,
                                                      int* __restrict__ csr_src,
                                                      float* __restrict__ csr_w, int n) {
    int e = blockIdx.x * 256 + threadIdx.x;
    if (e < n) {
        int d = dst[e];
        int pos = atomicAdd(&cursor[d], 1);
        csr_src[pos] = src[e];
        csr_w[pos] = w[e];
    }
}

// ---------------- GEMM, N=128 (fp32, vector ALU) ----------------
// C[M x 128] = A[M x K] @ B[K x 128]; K multiple of 32; tile 64(M) x 128(N), KC=32.
__global__ __launch_bounds__(256) void gemm_n128(const float* __restrict__ A,
                                                 const float* __restrict__ Bm,
                                                 float* __restrict__ C, int M, int K) {
    __shared__ float As[64][36];   // padded: 16B-aligned rows, conflict-free reads
    __shared__ float Bs[32][128];
    const int tid = threadIdx.x;
    const int tm = tid >> 4;   // 0..15 -> 4 rows each
    const int tn = tid & 15;   // 0..15 -> cols {tn*4..+3} U {64+tn*4..+3}
    const int row0 = blockIdx.x * 64;

    float acc[4][8];
#pragma unroll
    for (int i = 0; i < 4; ++i)
#pragma unroll
        for (int j = 0; j < 8; ++j) acc[i][j] = 0.f;

    for (int kc = 0; kc < K; kc += 32) {
        // stage A: 64x32 floats = 512 float4, 2 per thread
#pragma unroll
        for (int q = tid; q < 512; q += 256) {
            int r = q >> 3;
            int c = (q & 7) << 2;
            int row = row0 + r;
            float4 v = make_float4(0.f, 0.f, 0.f, 0.f);
            if (row < M) v = *(const float4*)&A[(size_t)row * K + kc + c];
            *(float4*)&As[r][c] = v;
        }
        // stage B: 32x128 floats = 1024 float4, 4 per thread
#pragma unroll
        for (int q = tid; q < 1024; q += 256) {
            int r = q >> 5;
            int c = (q & 31) << 2;
            *(float4*)&Bs[r][c] = *(const float4*)&Bm[(size_t)(kc + r) * 128 + c];
        }
        __syncthreads();

#pragma unroll
        for (int k = 0; k < 32; k += 4) {
            float a[4][4];
#pragma unroll
            for (int i = 0; i < 4; ++i) {
                float4 v = *(const float4*)&As[tm * 4 + i][k];
                a[i][0] = v.x; a[i][1] = v.y; a[i][2] = v.z; a[i][3] = v.w;
            }
#pragma unroll
            for (int kk = 0; kk < 4; ++kk) {
                float4 b0 = *(const float4*)&Bs[k + kk][tn * 4];
                float4 b1 = *(const float4*)&Bs[k + kk][64 + tn * 4];
#pragma unroll
                for (int i = 0; i < 4; ++i) {
                    acc[i][0] += a[i][kk] * b0.x;
                    acc[i][1] += a[i][kk] * b0.y;
                    acc[i][2] += a[i][kk] * b0.z;
                    acc[i][3] += a[i][kk] * b0.w;
                    acc[i][4] += a[i][kk] * b1.x;
                    acc[i][5] += a[i][kk] * b1.y;
                    acc[i][6] += a[i][kk] * b1.z;
                    acc[i][7] += a[i][kk] * b1.w;
                }
            }
        }
        __syncthreads();
    }

#pragma unroll
    for (int i = 0; i < 4; ++i) {
        int row = row0 + tm * 4 + i;
        if (row < M) {
            *(float4*)&C[(size_t)row * 128 + tn * 4] =
                make_float4(acc[i][0], acc[i][1], acc[i][2], acc[i][3]);
            *(float4*)&C[(size_t)row * 128 + 64 + tn * 4] =
                make_float4(acc[i][4], acc[i][5], acc[i][6], acc[i][7]);
        }
    }
}

// ---------------- GEMM, N=40, K=128 ----------------
__global__ __launch_bounds__(256) void gemm_n40(const float* __restrict__ A,
                                                const float* __restrict__ Bm,
                                                float* __restrict__ C, int M) {
    __shared__ float As[64][132];       // pad: conflict-free column reads
    __shared__ float Bs[128 * 40];
    const int tid = threadIdx.x;
    const int tr = tid >> 2;  // 0..63 (row)
    const int tc = tid & 3;   // 0..3  (10 cols each)
    const int row0 = blockIdx.x * 64;

    // stage A tile 64x128 = 2048 float4, 8 per thread
#pragma unroll
    for (int q = tid; q < 2048; q += 256) {
        int r = q >> 5;
        int c = (q & 31) << 2;
        int row = row0 + r;
        float4 v = make_float4(0.f, 0.f, 0.f, 0.f);
        if (row < M) v = *(const float4*)&A[(size_t)row * 128 + c];
        *(float4*)&As[r][c] = v;
    }
    // stage B (full 128x40)
    for (int q = tid; q < 128 * 40; q += 256) Bs[q] = Bm[q];
    __syncthreads();

    float acc[10];
#pragma unroll
    for (int j = 0; j < 10; ++j) acc[j] = 0.f;

    for (int k = 0; k < 128; ++k) {
        float a = As[tr][k];
#pragma unroll
        for (int j = 0; j < 10; ++j) acc[j] += a * Bs[k * 40 + tc * 10 + j];
    }

    int row = row0 + tr;
    if (row < M) {
#pragma unroll
        for (int j = 0; j < 10; ++j) C[(size_t)row * 40 + tc * 10 + j] = acc[j];
    }
}

// ---------------- SpMM (CSR gather) + bias + optional ReLU, feat=128 ----------------
// one wave per dst node; lane f covers features {2f, 2f+1}
__global__ __launch_bounds__(256) void spmm_bias_relu(const float* __restrict__ t,
                                                      const int* __restrict__ row_ptr,
                                                      const int* __restrict__ csr_src,
                                                      const float* __restrict__ csr_w,
                                                      const float* __restrict__ bias,
                                                      float* __restrict__ out,
                                                      int do_relu) {
    const int node = blockIdx.x * 4 + (threadIdx.x >> 6);
    const int lane = threadIdx.x & 63;
    const int e0 = row_ptr[node];
    const int e1 = row_ptr[node + 1];
    float ax = 0.f, ay = 0.f;
    for (int e = e0; e < e1; ++e) {
        int s = csr_src[e];
        float w = csr_w[e];
        float2 v = *(const float2*)&t[(size_t)s * 128 + lane * 2];
        ax += w * v.x;
        ay += w * v.y;
    }
    float2 b = *(const float2*)&bias[lane * 2];
    ax += b.x;
    ay += b.y;
    if (do_relu) {
        ax = fmaxf(ax, 0.f);
        ay = fmaxf(ay, 0.f);
    }
    float2 r;
    r.x = ax;
    r.y = ay;
    *(float2*)&out[(size_t)node * 128 + lane * 2] = r;
}

// ---------------- SpMM feat=40 + bias + log_softmax ----------------
__global__ __launch_bounds__(256) void spmm_logsoftmax(const float* __restrict__ t,
                                                       const int* __restrict__ row_ptr,
                                                       const int* __restrict__ csr_src,
                                                       const float* __restrict__ csr_w,
                                                       const float* __restrict__ bias,
                                                       float* __restrict__ out) {
    const int node = blockIdx.x * 4 + (threadIdx.x >> 6);
    const int lane = threadIdx.x & 63;
    const int e0 = row_ptr[node];
    const int e1 = row_ptr[node + 1];
    const bool act = lane < NCLASS;
    float acc = 0.f;
    for (int e = e0; e < e1; ++e) {
        int s = csr_src[e];
        float w = csr_w[e];
        if (act) acc += w * t[(size_t)s * NCLASS + lane];
    }
    float logit = act ? (acc + bias[lane]) : -INFINITY;
    float m = logit;
#pragma unroll
    for (int off = 32; off; off >>= 1) m = fmaxf(m, __shfl_xor(m, off));
    float ex = act ? __expf(logit - m) : 0.f;
    float ssum = ex;
#pragma unroll
    for (int off = 32; off; off >>= 1) ssum += __shfl_xor(ssum, off);
    if (act) out[(size_t)node * NCLASS + lane] = logit - m - __logf(ssum);
}

// ---------------- launch ----------------

extern "C" void kernel_launch(void* const* d_in, const int* in_sizes, int n_in,
                              void* d_out, int out_size, void* d_ws, size_t ws_size,
                              hipStream_t stream) {
    const float* x = (const float*)d_in[0];
    const int* edge_src = (const int*)d_in[1];
    const int* edge_dst = (const int*)d_in[2];
    const float* edge_weight = (const float*)d_in[3];
    const float* W1 = (const float*)d_in[4];
    const float* b1 = (const float*)d_in[5];
    const float* Wh = (const float*)d_in[6];
    const float* bh = (const float*)d_in[7];
    const float* W2 = (const float*)d_in[8];
    const float* b2 = (const float*)d_in[9];
    float* out = (float*)d_out;

    // workspace carve-up (aligned to 512B)
    size_t off = 0;
    auto carve = [&](size_t bytes) {
        void* p = (char*)d_ws + off;
        off += (bytes + 511) & ~(size_t)511;
        return p;
    };
    float* t = (float*)carve((size_t)N_NODES * 128 * 4);   // transform output (also 50000x40)
    float* h = (float*)carve((size_t)N_NODES * 128 * 4);   // aggregated activation
    int* counts = (int*)carve((size_t)N_NODES * 4);
    int* row_ptr = (int*)carve((size_t)(N_NODES + 4) * 4);
    int* cursor = (int*)carve((size_t)N_NODES * 4);
    int* csr_src = (int*)carve((size_t)N_EDGES * 4);
    float* csr_w = (float*)carve((size_t)N_EDGES * 4);
    (void)ws_size; (void)n_in; (void)in_sizes; (void)out_size;

    const int nodeBlocks = (N_NODES + 255) / 256;        // 196
    const int edgeBlocks = (N_EDGES + 255) / 256;        // 6250
    const int spmmBlocks = N_NODES / 4;                  // 12500
    const int gemmBlocks = (N_NODES + 63) / 64;          // 782

    // Build CSR (by destination)
    zero_counts<<<nodeBlocks, 256, 0, stream>>>(counts, N_NODES);
    hist_kernel<<<edgeBlocks, 256, 0, stream>>>(edge_dst, counts, N_EDGES);
    scan_kernel<<<1, 1024, 0, stream>>>(counts, row_ptr, cursor, N_NODES);
    scatter_kernel<<<edgeBlocks, 256, 0, stream>>>(edge_src, edge_dst, edge_weight,
                                                   cursor, csr_src, csr_w, N_EDGES);

    // Layer 1: t = x @ W1 ; h = relu(spmm(t) + b1)
    gemm_n128<<<gemmBlocks, 256, 0, stream>>>(x, W1, t, N_NODES, NFEAT);
    spmm_bias_relu<<<spmmBlocks, 256, 0, stream>>>(t, row_ptr, csr_src, csr_w, b1, h, 1);

    // Layer 2: t = h @ Wh ; h = relu(spmm(t) + bh)
    gemm_n128<<<gemmBlocks, 256, 0, stream>>>(h, Wh, t, N_NODES, NHID);
    spmm_bias_relu<<<spmmBlocks, 256, 0, stream>>>(t, row_ptr, csr_src, csr_w, bh, h, 1);

    // Layer 3: t = h @ W2 (N=40) ; out = log_softmax(spmm(t) + b2)
    gemm_n40<<<gemmBlocks, 256, 0, stream>>>(h, W2, t, N_NODES);
    spmm_logsoftmax<<<spmmBlocks, 256, 0, stream>>>(t, row_ptr, csr_src, csr_w, b2, out);
}

// Round 2
// 732.784 us; speedup vs baseline: 1.4040x; 1.4040x over previous
//
#include <hip/hip_runtime.h>
#include <hip/hip_bf16.h>
#include <math.h>

#define N_NODES 50000
#define N_EDGES 1600000
#define NFEAT 512
#define NHID 128
#define NCLASS 40

typedef __attribute__((ext_vector_type(8))) short bf16x8;
typedef __attribute__((ext_vector_type(4))) float f32x4;

static __device__ __forceinline__ float asfloat_u32(unsigned int u) {
    union { unsigned int u; float f; } c;
    c.u = u;
    return c.f;
}
static __device__ __forceinline__ unsigned short f2bf(float f) {
    union { float f; unsigned int u; } c;
    c.f = f;
    unsigned int r = c.u + 0x7FFFu + ((c.u >> 16) & 1u);  // RTN-even
    return (unsigned short)(r >> 16);
}

// ---------------- CSR build ----------------

__global__ __launch_bounds__(256) void zero_counts(int* counts, int n) {
    int i = blockIdx.x * 256 + threadIdx.x;
    if (i < n) counts[i] = 0;
}

__global__ __launch_bounds__(256) void hist_kernel(const int* __restrict__ dst,
                                                   int* __restrict__ counts, int n) {
    int e = blockIdx.x * 256 + threadIdx.x;
    if (e < n) atomicAdd(&counts[dst[e]], 1);
}

__global__ __launch_bounds__(1024) void scan_kernel(const int* __restrict__ counts,
                                                    int* __restrict__ row_ptr,
                                                    int* __restrict__ cursor, int n) {
    __shared__ int sums[1024];
    const int tid = threadIdx.x;
    const int chunk = (n + 1023) / 1024;
    const int start = tid * chunk;
    const int end = min(start + chunk, n);
    int s = 0;
    for (int i = start; i < end; ++i) s += counts[i];
    sums[tid] = s;
    __syncthreads();
    for (int off = 1; off < 1024; off <<= 1) {
        int v = (tid >= off) ? sums[tid - off] : 0;
        __syncthreads();
        sums[tid] += v;
        __syncthreads();
    }
    int prev = (tid == 0) ? 0 : sums[tid - 1];
    int run = prev;
    for (int i = start; i < end; ++i) {
        row_ptr[i] = run;
        cursor[i] = run;
        run += counts[i];
    }
    if (end == n) row_ptr[n] = run;
}

__global__ __launch_bounds__(256) void scatter_kernel(const int* __restrict__ src,
                                                      const int* __restrict__ dst,
                                                      const float* __restrict__ w,
                                                      int* __restrict__ cursor,
                                                      int* __restrict__ csr_src,
                                                      float* __restrict__ csr_w, int n) {
    int e = blockIdx.x * 256 + threadIdx.x;
    if (e < n) {
        int d = dst[e];
        int pos = atomicAdd(&cursor[d], 1);
        csr_src[pos] = src[e];
        csr_w[pos] = w[e];
    }
}

// ---------------- weight transpose + bf16 convert ----------------
// Wt[n][k] = bf16(W[k][n]); W is [K][N] row-major, N<=128
__global__ __launch_bounds__(256) void transpose_to_bf16(const float* __restrict__ W,
                                                         unsigned short* __restrict__ Wt,
                                                         int K, int N) {
    int idx = blockIdx.x * 256 + threadIdx.x;
    if (idx < K * N) {
        int k = idx / N;
        int n = idx - k * N;
        Wt[(size_t)n * K + k] = f2bf(W[idx]);
    }
}

// ---------------- MFMA GEMM, N=128 ----------------
// C[M x 128](bf16) = A[M x K] @ Wt^T ; Wt is [128][K] bf16 (pre-transposed B).
// One wave per 16 rows; 8 MFMA tiles (16x16x32 bf16) cover all 128 cols.
// A-frag: A[m=lane&15][k=quad*8+j]; B-frag: B[k=quad*8+j][n=lane&15] = Wt[n][k];
// C/D: row=quad*4+reg, col=lane&15  (m89/m91-verified layouts)
template <bool A_IS_BF16>
__global__ __launch_bounds__(256) void gemm_mfma_n128(const void* __restrict__ Ap,
                                                      const unsigned short* __restrict__ Wt,
                                                      unsigned short* __restrict__ C,
                                                      const int M, const int K) {
    const int gwave = (blockIdx.x * 256 + threadIdx.x) >> 6;
    const int m0 = gwave * 16;
    if (m0 >= M) return;
    const int lane = threadIdx.x & 63;
    const int ln = lane & 15;
    const int quad = lane >> 4;

    f32x4 acc[8];
#pragma unroll
    for (int t = 0; t < 8; ++t) acc[t] = (f32x4){0.f, 0.f, 0.f, 0.f};

    const int row = m0 + ln;  // M % 16 == 0 so always valid
    for (int kc = 0; kc < K; kc += 32) {
        bf16x8 a;
        if (A_IS_BF16) {
            a = *(const bf16x8*)((const unsigned short*)Ap + (size_t)row * K + kc + quad * 8);
        } else {
            const float* Af = (const float*)Ap + (size_t)row * K + kc + quad * 8;
            float4 f0 = *(const float4*)(Af);
            float4 f1 = *(const float4*)(Af + 4);
            a[0] = (short)f2bf(f0.x); a[1] = (short)f2bf(f0.y);
            a[2] = (short)f2bf(f0.z); a[3] = (short)f2bf(f0.w);
            a[4] = (short)f2bf(f1.x); a[5] = (short)f2bf(f1.y);
            a[6] = (short)f2bf(f1.z); a[7] = (short)f2bf(f1.w);
        }
#pragma unroll
        for (int t = 0; t < 8; ++t) {
            bf16x8 b = *(const bf16x8*)(Wt + (size_t)(t * 16 + ln) * K + kc + quad * 8);
            acc[t] = __builtin_amdgcn_mfma_f32_16x16x32_bf16(a, b, acc[t], 0, 0, 0);
        }
    }

#pragma unroll
    for (int t = 0; t < 8; ++t)
#pragma unroll
        for (int r = 0; r < 4; ++r)
            C[(size_t)(m0 + quad * 4 + r) * 128 + t * 16 + ln] = f2bf(acc[t][r]);
}

// ---------------- GEMM, N=40, K=128, A in bf16 ----------------
__global__ __launch_bounds__(256) void gemm_n40_bf16A(const unsigned short* __restrict__ A,
                                                      const float* __restrict__ Bm,
                                                      float* __restrict__ C, int M) {
    __shared__ float As[64][132];
    __shared__ float Bs[128 * 40];
    const int tid = threadIdx.x;
    const int tr = tid >> 2;
    const int tc = tid & 3;
    const int row0 = blockIdx.x * 64;

    // stage A tile 64x128 bf16 -> fp32 LDS; 8B (4 bf16) per access
#pragma unroll
    for (int q = tid; q < 2048; q += 256) {
        int r = q >> 5;
        int c = (q & 31) << 2;
        int row = row0 + r;
        uint2 u = make_uint2(0u, 0u);
        if (row < M) u = *(const uint2*)(A + (size_t)row * 128 + c);
        As[r][c + 0] = asfloat_u32(u.x << 16);
        As[r][c + 1] = asfloat_u32(u.x & 0xFFFF0000u);
        As[r][c + 2] = asfloat_u32(u.y << 16);
        As[r][c + 3] = asfloat_u32(u.y & 0xFFFF0000u);
    }
    for (int q = tid; q < 128 * 40; q += 256) Bs[q] = Bm[q];
    __syncthreads();

    float acc[10];
#pragma unroll
    for (int j = 0; j < 10; ++j) acc[j] = 0.f;

    for (int k = 0; k < 128; ++k) {
        float a = As[tr][k];
#pragma unroll
        for (int j = 0; j < 10; ++j) acc[j] += a * Bs[k * 40 + tc * 10 + j];
    }

    int row = row0 + tr;
    if (row < M) {
#pragma unroll
        for (int j = 0; j < 10; ++j) C[(size_t)row * 40 + tc * 10 + j] = acc[j];
    }
}

// ---------------- SpMM (CSR gather, bf16 rows) + bias + ReLU, feat=128 ----------------
// one wave per dst node; lane f covers features {2f, 2f+1} via one 4B load; edge loop x4
__global__ __launch_bounds__(256) void spmm_bias_relu_bf16(const unsigned short* __restrict__ t,
                                                           const int* __restrict__ row_ptr,
                                                           const int* __restrict__ csr_src,
                                                           const float* __restrict__ csr_w,
                                                           const float* __restrict__ bias,
                                                           unsigned short* __restrict__ out) {
    const int node = blockIdx.x * 4 + (threadIdx.x >> 6);
    const int lane = threadIdx.x & 63;
    const int e0 = row_ptr[node];
    const int e1 = row_ptr[node + 1];
    float ax = 0.f, ay = 0.f;
    int e = e0;
    for (; e + 4 <= e1; e += 4) {
        int s0 = csr_src[e], s1 = csr_src[e + 1], s2 = csr_src[e + 2], s3 = csr_src[e + 3];
        float w0 = csr_w[e], w1 = csr_w[e + 1], w2 = csr_w[e + 2], w3 = csr_w[e + 3];
        unsigned int v0 = *(const unsigned int*)(t + (size_t)s0 * 128 + lane * 2);
        unsigned int v1 = *(const unsigned int*)(t + (size_t)s1 * 128 + lane * 2);
        unsigned int v2 = *(const unsigned int*)(t + (size_t)s2 * 128 + lane * 2);
        unsigned int v3 = *(const unsigned int*)(t + (size_t)s3 * 128 + lane * 2);
        ax += w0 * asfloat_u32(v0 << 16);
        ay += w0 * asfloat_u32(v0 & 0xFFFF0000u);
        ax += w1 * asfloat_u32(v1 << 16);
        ay += w1 * asfloat_u32(v1 & 0xFFFF0000u);
        ax += w2 * asfloat_u32(v2 << 16);
        ay += w2 * asfloat_u32(v2 & 0xFFFF0000u);
        ax += w3 * asfloat_u32(v3 << 16);
        ay += w3 * asfloat_u32(v3 & 0xFFFF0000u);
    }
    for (; e < e1; ++e) {
        int s = csr_src[e];
        float w = csr_w[e];
        unsigned int v = *(const unsigned int*)(t + (size_t)s * 128 + lane * 2);
        ax += w * asfloat_u32(v << 16);
        ay += w * asfloat_u32(v & 0xFFFF0000u);
    }
    float2 b = *(const float2*)&bias[lane * 2];
    ax = fmaxf(ax + b.x, 0.f);
    ay = fmaxf(ay + b.y, 0.f);
    unsigned int packed = ((unsigned int)f2bf(ax)) | (((unsigned int)f2bf(ay)) << 16);
    *(unsigned int*)(out + (size_t)node * 128 + lane * 2) = packed;
}

// ---------------- SpMM feat=40 (fp32) + bias + log_softmax ----------------
__global__ __launch_bounds__(256) void spmm_logsoftmax(const float* __restrict__ t,
                                                       const int* __restrict__ row_ptr,
                                                       const int* __restrict__ csr_src,
                                                       const float* __restrict__ csr_w,
                                                       const float* __restrict__ bias,
                                                       float* __restrict__ out) {
    const int node = blockIdx.x * 4 + (threadIdx.x >> 6);
    const int lane = threadIdx.x & 63;
    const int e0 = row_ptr[node];
    const int e1 = row_ptr[node + 1];
    const bool act = lane < NCLASS;
    float acc = 0.f;
    int e = e0;
    for (; e + 4 <= e1; e += 4) {
        int s0 = csr_src[e], s1 = csr_src[e + 1], s2 = csr_src[e + 2], s3 = csr_src[e + 3];
        float w0 = csr_w[e], w1 = csr_w[e + 1], w2 = csr_w[e + 2], w3 = csr_w[e + 3];
        if (act) {
            float v0 = t[(size_t)s0 * NCLASS + lane];
            float v1 = t[(size_t)s1 * NCLASS + lane];
            float v2 = t[(size_t)s2 * NCLASS + lane];
            float v3 = t[(size_t)s3 * NCLASS + lane];
            acc += w0 * v0 + w1 * v1 + w2 * v2 + w3 * v3;
        }
    }
    for (; e < e1; ++e) {
        if (act) acc += csr_w[e] * t[(size_t)csr_src[e] * NCLASS + lane];
    }
    float logit = act ? (acc + bias[lane]) : -INFINITY;
    float m = logit;
#pragma unroll
    for (int off = 32; off; off >>= 1) m = fmaxf(m, __shfl_xor(m, off));
    float ex = act ? __expf(logit - m) : 0.f;
    float ssum = ex;
#pragma unroll
    for (int off = 32; off; off >>= 1) ssum += __shfl_xor(ssum, off);
    if (act) out[(size_t)node * NCLASS + lane] = logit - m - __logf(ssum);
}

// ---------------- launch ----------------

extern "C" void kernel_launch(void* const* d_in, const int* in_sizes, int n_in,
                              void* d_out, int out_size, void* d_ws, size_t ws_size,
                              hipStream_t stream) {
    const float* x = (const float*)d_in[0];
    const int* edge_src = (const int*)d_in[1];
    const int* edge_dst = (const int*)d_in[2];
    const float* edge_weight = (const float*)d_in[3];
    const float* W1 = (const float*)d_in[4];
    const float* b1 = (const float*)d_in[5];
    const float* Wh = (const float*)d_in[6];
    const float* bh = (const float*)d_in[7];
    const float* W2 = (const float*)d_in[8];
    const float* b2 = (const float*)d_in[9];
    float* out = (float*)d_out;

    size_t off = 0;
    auto carve = [&](size_t bytes) {
        void* p = (char*)d_ws + off;
        off += (bytes + 511) & ~(size_t)511;
        return p;
    };
    unsigned short* tb = (unsigned short*)carve((size_t)N_NODES * 128 * 2);  // bf16 transform
    unsigned short* hb = (unsigned short*)carve((size_t)N_NODES * 128 * 2);  // bf16 activation
    float* t3 = (float*)carve((size_t)N_NODES * NCLASS * 4);                 // fp32 last transform
    unsigned short* Wt1 = (unsigned short*)carve((size_t)NFEAT * NHID * 2);
    unsigned short* Wth = (unsigned short*)carve((size_t)NHID * NHID * 2);
    int* counts = (int*)carve((size_t)N_NODES * 4);
    int* row_ptr = (int*)carve((size_t)(N_NODES + 4) * 4);
    int* cursor = (int*)carve((size_t)N_NODES * 4);
    int* csr_src = (int*)carve((size_t)N_EDGES * 4);
    float* csr_w = (float*)carve((size_t)N_EDGES * 4);
    (void)ws_size; (void)n_in; (void)in_sizes; (void)out_size;

    const int nodeBlocks = (N_NODES + 255) / 256;
    const int edgeBlocks = (N_EDGES + 255) / 256;
    const int spmmBlocks = N_NODES / 4;
    const int waveBlocks = ((N_NODES / 16) + 3) / 4;   // 782: 4 waves/block, 16 rows/wave
    const int gemmBlocks = (N_NODES + 63) / 64;

    // CSR build
    zero_counts<<<nodeBlocks, 256, 0, stream>>>(counts, N_NODES);
    hist_kernel<<<edgeBlocks, 256, 0, stream>>>(edge_dst, counts, N_EDGES);
    scan_kernel<<<1, 1024, 0, stream>>>(counts, row_ptr, cursor, N_NODES);
    scatter_kernel<<<edgeBlocks, 256, 0, stream>>>(edge_src, edge_dst, edge_weight,
                                                   cursor, csr_src, csr_w, N_EDGES);

    // weight prep
    transpose_to_bf16<<<(NFEAT * NHID + 255) / 256, 256, 0, stream>>>(W1, Wt1, NFEAT, NHID);
    transpose_to_bf16<<<(NHID * NHID + 255) / 256, 256, 0, stream>>>(Wh, Wth, NHID, NHID);

    // Layer 1
    gemm_mfma_n128<false><<<waveBlocks, 256, 0, stream>>>(x, Wt1, tb, N_NODES, NFEAT);
    spmm_bias_relu_bf16<<<spmmBlocks, 256, 0, stream>>>(tb, row_ptr, csr_src, csr_w, b1, hb);

    // Layer 2
    gemm_mfma_n128<true><<<waveBlocks, 256, 0, stream>>>(hb, Wth, tb, N_NODES, NHID);
    spmm_bias_relu_bf16<<<spmmBlocks, 256, 0, stream>>>(tb, row_ptr, csr_src, csr_w, bh, hb);

    // Layer 3
    gemm_n40_bf16A<<<gemmBlocks, 256, 0, stream>>>(hb, W2, t3, N_NODES);
    spmm_logsoftmax<<<spmmBlocks, 256, 0, stream>>>(t3, row_ptr, csr_src, csr_w, b2, out);
}

// Round 3
// 632.942 us; speedup vs baseline: 1.6255x; 1.1577x over previous
//
#include <hip/hip_runtime.h>
#include <hip/hip_bf16.h>
#include <math.h>

#define N_NODES 50000
#define N_EDGES 1600000
#define NFEAT 512
#define NHID 128
#define NCLASS 40

typedef __attribute__((ext_vector_type(8))) short bf16x8;
typedef __attribute__((ext_vector_type(4))) float f32x4;

static __device__ __forceinline__ float asfloat_u32(unsigned int u) {
    union { unsigned int u; float f; } c;
    c.u = u;
    return c.f;
}
static __device__ __forceinline__ unsigned int asu32_f(float f) {
    union { float f; unsigned int u; } c;
    c.f = f;
    return c.u;
}
static __device__ __forceinline__ unsigned short f2bf(float f) {
    union { float f; unsigned int u; } c;
    c.f = f;
    unsigned int r = c.u + 0x7FFFu + ((c.u >> 16) & 1u);  // RTN-even
    return (unsigned short)(r >> 16);
}

// ---------------- CSR build ----------------

__global__ __launch_bounds__(256) void zero_counts(int* counts, int n) {
    int i = blockIdx.x * 256 + threadIdx.x;
    if (i < n) counts[i] = 0;
}

__global__ __launch_bounds__(256) void hist_kernel(const int* __restrict__ dst,
                                                   int* __restrict__ counts, int n) {
    int e = blockIdx.x * 256 + threadIdx.x;
    if (e < n) atomicAdd(&counts[dst[e]], 1);
}

// pass 1: per-block (256 elems) reduction
__global__ __launch_bounds__(256) void scan_reduce(const int* __restrict__ counts,
                                                   int* __restrict__ blockSums, int n) {
    __shared__ int red[256];
    int i = blockIdx.x * 256 + threadIdx.x;
    red[threadIdx.x] = (i < n) ? counts[i] : 0;
    __syncthreads();
#pragma unroll
    for (int off = 128; off; off >>= 1) {
        if (threadIdx.x < off) red[threadIdx.x] += red[threadIdx.x + off];
        __syncthreads();
    }
    if (threadIdx.x == 0) blockSums[blockIdx.x] = red[0];
}

// pass 2: single block scans nb (<=256) block sums -> exclusive offsets; writes total
__global__ __launch_bounds__(256) void scan_tops(const int* __restrict__ blockSums,
                                                 int* __restrict__ blockOffs,
                                                 int* __restrict__ totalOut, int nb) {
    __shared__ int s[256];
    int v = (threadIdx.x < nb) ? blockSums[threadIdx.x] : 0;
    s[threadIdx.x] = v;
    __syncthreads();
    for (int off = 1; off < 256; off <<= 1) {
        int t = (threadIdx.x >= off) ? s[threadIdx.x - off] : 0;
        __syncthreads();
        s[threadIdx.x] += t;
        __syncthreads();
    }
    if (threadIdx.x < nb) blockOffs[threadIdx.x] = s[threadIdx.x] - v;
    if (threadIdx.x == nb - 1) totalOut[0] = s[threadIdx.x];
}

// pass 3: block-local exclusive scan + block offset -> row_ptr, cursor
__global__ __launch_bounds__(256) void scan_final(const int* __restrict__ counts,
                                                  const int* __restrict__ blockOffs,
                                                  int* __restrict__ row_ptr,
                                                  int* __restrict__ cursor, int n) {
    __shared__ int s[256];
    int i = blockIdx.x * 256 + threadIdx.x;
    int v = (i < n) ? counts[i] : 0;
    s[threadIdx.x] = v;
    __syncthreads();
    for (int off = 1; off < 256; off <<= 1) {
        int t = (threadIdx.x >= off) ? s[threadIdx.x - off] : 0;
        __syncthreads();
        s[threadIdx.x] += t;
        __syncthreads();
    }
    int excl = s[threadIdx.x] - v + blockOffs[blockIdx.x];
    if (i < n) {
        row_ptr[i] = excl;
        cursor[i] = excl;
    }
}

// scatter edges into paired (src, weight) 8B records — one scattered store per edge
__global__ __launch_bounds__(256) void scatter_kernel(const int* __restrict__ src,
                                                      const int* __restrict__ dst,
                                                      const float* __restrict__ w,
                                                      int* __restrict__ cursor,
                                                      uint2* __restrict__ pairs, int n) {
    int e = blockIdx.x * 256 + threadIdx.x;
    if (e < n) {
        int d = dst[e];
        int pos = atomicAdd(&cursor[d], 1);
        uint2 pr;
        pr.x = (unsigned int)src[e];
        pr.y = asu32_f(w[e]);
        pairs[pos] = pr;
    }
}

// ---------------- weight transpose + bf16 convert ----------------
__global__ __launch_bounds__(256) void transpose_to_bf16(const float* __restrict__ W,
                                                         unsigned short* __restrict__ Wt,
                                                         int K, int N) {
    int idx = blockIdx.x * 256 + threadIdx.x;
    if (idx < K * N) {
        int k = idx / N;
        int n = idx - k * N;
        Wt[(size_t)n * K + k] = f2bf(W[idx]);
    }
}

// ---------------- MFMA GEMM, N=128 ----------------
template <bool A_IS_BF16>
__global__ __launch_bounds__(256) void gemm_mfma_n128(const void* __restrict__ Ap,
                                                      const unsigned short* __restrict__ Wt,
                                                      unsigned short* __restrict__ C,
                                                      const int M, const int K) {
    const int gwave = (blockIdx.x * 256 + threadIdx.x) >> 6;
    const int m0 = gwave * 16;
    if (m0 >= M) return;
    const int lane = threadIdx.x & 63;
    const int ln = lane & 15;
    const int quad = lane >> 4;

    f32x4 acc[8];
#pragma unroll
    for (int t = 0; t < 8; ++t) acc[t] = (f32x4){0.f, 0.f, 0.f, 0.f};

    const int row = m0 + ln;
    for (int kc = 0; kc < K; kc += 32) {
        bf16x8 a;
        if (A_IS_BF16) {
            a = *(const bf16x8*)((const unsigned short*)Ap + (size_t)row * K + kc + quad * 8);
        } else {
            const float* Af = (const float*)Ap + (size_t)row * K + kc + quad * 8;
            float4 f0 = *(const float4*)(Af);
            float4 f1 = *(const float4*)(Af + 4);
            a[0] = (short)f2bf(f0.x); a[1] = (short)f2bf(f0.y);
            a[2] = (short)f2bf(f0.z); a[3] = (short)f2bf(f0.w);
            a[4] = (short)f2bf(f1.x); a[5] = (short)f2bf(f1.y);
            a[6] = (short)f2bf(f1.z); a[7] = (short)f2bf(f1.w);
        }
#pragma unroll
        for (int t = 0; t < 8; ++t) {
            bf16x8 b = *(const bf16x8*)(Wt + (size_t)(t * 16 + ln) * K + kc + quad * 8);
            acc[t] = __builtin_amdgcn_mfma_f32_16x16x32_bf16(a, b, acc[t], 0, 0, 0);
        }
    }

#pragma unroll
    for (int t = 0; t < 8; ++t)
#pragma unroll
        for (int r = 0; r < 4; ++r)
            C[(size_t)(m0 + quad * 4 + r) * 128 + t * 16 + ln] = f2bf(acc[t][r]);
}

// ---------------- GEMM, N=40, K=128, A in bf16 ----------------
__global__ __launch_bounds__(256) void gemm_n40_bf16A(const unsigned short* __restrict__ A,
                                                      const float* __restrict__ Bm,
                                                      float* __restrict__ C, int M) {
    __shared__ float As[64][132];
    __shared__ float Bs[128 * 40];
    const int tid = threadIdx.x;
    const int tr = tid >> 2;
    const int tc = tid & 3;
    const int row0 = blockIdx.x * 64;

#pragma unroll
    for (int q = tid; q < 2048; q += 256) {
        int r = q >> 5;
        int c = (q & 31) << 2;
        int row = row0 + r;
        uint2 u = make_uint2(0u, 0u);
        if (row < M) u = *(const uint2*)(A + (size_t)row * 128 + c);
        As[r][c + 0] = asfloat_u32(u.x << 16);
        As[r][c + 1] = asfloat_u32(u.x & 0xFFFF0000u);
        As[r][c + 2] = asfloat_u32(u.y << 16);
        As[r][c + 3] = asfloat_u32(u.y & 0xFFFF0000u);
    }
    for (int q = tid; q < 128 * 40; q += 256) Bs[q] = Bm[q];
    __syncthreads();

    float acc[10];
#pragma unroll
    for (int j = 0; j < 10; ++j) acc[j] = 0.f;

    for (int k = 0; k < 128; ++k) {
        float a = As[tr][k];
#pragma unroll
        for (int j = 0; j < 10; ++j) acc[j] += a * Bs[k * 40 + tc * 10 + j];
    }

    int row = row0 + tr;
    if (row < M) {
#pragma unroll
        for (int j = 0; j < 10; ++j) C[(size_t)row * 40 + tc * 10 + j] = acc[j];
    }
}

// ---------------- SpMM (CSR gather, bf16 rows) + bias + ReLU, feat=128 ----------------
__global__ __launch_bounds__(256) void spmm_bias_relu_bf16(const unsigned short* __restrict__ t,
                                                           const int* __restrict__ row_ptr,
                                                           const uint2* __restrict__ pairs,
                                                           const float* __restrict__ bias,
                                                           unsigned short* __restrict__ out) {
    const int node = blockIdx.x * 4 + (threadIdx.x >> 6);
    const int lane = threadIdx.x & 63;
    const int e0 = row_ptr[node];
    const int e1 = row_ptr[node + 1];
    float ax = 0.f, ay = 0.f;
    int e = e0;
    for (; e + 8 <= e1; e += 8) {
        uint2 p0 = pairs[e],     p1 = pairs[e + 1], p2 = pairs[e + 2], p3 = pairs[e + 3];
        uint2 p4 = pairs[e + 4], p5 = pairs[e + 5], p6 = pairs[e + 6], p7 = pairs[e + 7];
        unsigned int v0 = *(const unsigned int*)(t + (size_t)p0.x * 128 + lane * 2);
        unsigned int v1 = *(const unsigned int*)(t + (size_t)p1.x * 128 + lane * 2);
        unsigned int v2 = *(const unsigned int*)(t + (size_t)p2.x * 128 + lane * 2);
        unsigned int v3 = *(const unsigned int*)(t + (size_t)p3.x * 128 + lane * 2);
        unsigned int v4 = *(const unsigned int*)(t + (size_t)p4.x * 128 + lane * 2);
        unsigned int v5 = *(const unsigned int*)(t + (size_t)p5.x * 128 + lane * 2);
        unsigned int v6 = *(const unsigned int*)(t + (size_t)p6.x * 128 + lane * 2);
        unsigned int v7 = *(const unsigned int*)(t + (size_t)p7.x * 128 + lane * 2);
        float w0 = asfloat_u32(p0.y), w1 = asfloat_u32(p1.y);
        float w2 = asfloat_u32(p2.y), w3 = asfloat_u32(p3.y);
        float w4 = asfloat_u32(p4.y), w5 = asfloat_u32(p5.y);
        float w6 = asfloat_u32(p6.y), w7 = asfloat_u32(p7.y);
        ax += w0 * asfloat_u32(v0 << 16); ay += w0 * asfloat_u32(v0 & 0xFFFF0000u);
        ax += w1 * asfloat_u32(v1 << 16); ay += w1 * asfloat_u32(v1 & 0xFFFF0000u);
        ax += w2 * asfloat_u32(v2 << 16); ay += w2 * asfloat_u32(v2 & 0xFFFF0000u);
        ax += w3 * asfloat_u32(v3 << 16); ay += w3 * asfloat_u32(v3 & 0xFFFF0000u);
        ax += w4 * asfloat_u32(v4 << 16); ay += w4 * asfloat_u32(v4 & 0xFFFF0000u);
        ax += w5 * asfloat_u32(v5 << 16); ay += w5 * asfloat_u32(v5 & 0xFFFF0000u);
        ax += w6 * asfloat_u32(v6 << 16); ay += w6 * asfloat_u32(v6 & 0xFFFF0000u);
        ax += w7 * asfloat_u32(v7 << 16); ay += w7 * asfloat_u32(v7 & 0xFFFF0000u);
    }
    for (; e < e1; ++e) {
        uint2 p = pairs[e];
        float w = asfloat_u32(p.y);
        unsigned int v = *(const unsigned int*)(t + (size_t)p.x * 128 + lane * 2);
        ax += w * asfloat_u32(v << 16);
        ay += w * asfloat_u32(v & 0xFFFF0000u);
    }
    float2 b = *(const float2*)&bias[lane * 2];
    ax = fmaxf(ax + b.x, 0.f);
    ay = fmaxf(ay + b.y, 0.f);
    unsigned int packed = ((unsigned int)f2bf(ax)) | (((unsigned int)f2bf(ay)) << 16);
    *(unsigned int*)(out + (size_t)node * 128 + lane * 2) = packed;
}

// ---------------- SpMM feat=40 (fp32) + bias + log_softmax ----------------
__global__ __launch_bounds__(256) void spmm_logsoftmax(const float* __restrict__ t,
                                                       const int* __restrict__ row_ptr,
                                                       const uint2* __restrict__ pairs,
                                                       const float* __restrict__ bias,
                                                       float* __restrict__ out) {
    const int node = blockIdx.x * 4 + (threadIdx.x >> 6);
    const int lane = threadIdx.x & 63;
    const int e0 = row_ptr[node];
    const int e1 = row_ptr[node + 1];
    const bool act = lane < NCLASS;
    float acc = 0.f;
    int e = e0;
    for (; e + 4 <= e1; e += 4) {
        uint2 p0 = pairs[e], p1 = pairs[e + 1], p2 = pairs[e + 2], p3 = pairs[e + 3];
        if (act) {
            float v0 = t[(size_t)p0.x * NCLASS + lane];
            float v1 = t[(size_t)p1.x * NCLASS + lane];
            float v2 = t[(size_t)p2.x * NCLASS + lane];
            float v3 = t[(size_t)p3.x * NCLASS + lane];
            acc += asfloat_u32(p0.y) * v0 + asfloat_u32(p1.y) * v1 +
                   asfloat_u32(p2.y) * v2 + asfloat_u32(p3.y) * v3;
        }
    }
    for (; e < e1; ++e) {
        uint2 p = pairs[e];
        if (act) acc += asfloat_u32(p.y) * t[(size_t)p.x * NCLASS + lane];
    }
    float logit = act ? (acc + bias[lane]) : -INFINITY;
    float m = logit;
#pragma unroll
    for (int off = 32; off; off >>= 1) m = fmaxf(m, __shfl_xor(m, off));
    float ex = act ? __expf(logit - m) : 0.f;
    float ssum = ex;
#pragma unroll
    for (int off = 32; off; off >>= 1) ssum += __shfl_xor(ssum, off);
    if (act) out[(size_t)node * NCLASS + lane] = logit - m - __logf(ssum);
}

// ---------------- launch ----------------

extern "C" void kernel_launch(void* const* d_in, const int* in_sizes, int n_in,
                              void* d_out, int out_size, void* d_ws, size_t ws_size,
                              hipStream_t stream) {
    const float* x = (const float*)d_in[0];
    const int* edge_src = (const int*)d_in[1];
    const int* edge_dst = (const int*)d_in[2];
    const float* edge_weight = (const float*)d_in[3];
    const float* W1 = (const float*)d_in[4];
    const float* b1 = (const float*)d_in[5];
    const float* Wh = (const float*)d_in[6];
    const float* bh = (const float*)d_in[7];
    const float* W2 = (const float*)d_in[8];
    const float* b2 = (const float*)d_in[9];
    float* out = (float*)d_out;

    size_t off = 0;
    auto carve = [&](size_t bytes) {
        void* p = (char*)d_ws + off;
        off += (bytes + 511) & ~(size_t)511;
        return p;
    };
    unsigned short* tb = (unsigned short*)carve((size_t)N_NODES * 128 * 2);
    unsigned short* hb = (unsigned short*)carve((size_t)N_NODES * 128 * 2);
    float* t3 = (float*)carve((size_t)N_NODES * NCLASS * 4);
    unsigned short* Wt1 = (unsigned short*)carve((size_t)NFEAT * NHID * 2);
    unsigned short* Wth = (unsigned short*)carve((size_t)NHID * NHID * 2);
    int* counts = (int*)carve((size_t)N_NODES * 4);
    int* row_ptr = (int*)carve((size_t)(N_NODES + 4) * 4);
    int* cursor = (int*)carve((size_t)N_NODES * 4);
    int* blockSums = (int*)carve(256 * 4);
    int* blockOffs = (int*)carve(256 * 4);
    uint2* pairs = (uint2*)carve((size_t)N_EDGES * 8);
    (void)ws_size; (void)n_in; (void)in_sizes; (void)out_size;

    const int nodeBlocks = (N_NODES + 255) / 256;     // 196
    const int edgeBlocks = (N_EDGES + 255) / 256;     // 6250
    const int spmmBlocks = N_NODES / 4;               // 12500
    const int waveBlocks = ((N_NODES / 16) + 3) / 4;  // 782
    const int gemmBlocks = (N_NODES + 63) / 64;       // 782

    // CSR build
    zero_counts<<<nodeBlocks, 256, 0, stream>>>(counts, N_NODES);
    hist_kernel<<<edgeBlocks, 256, 0, stream>>>(edge_dst, counts, N_EDGES);
    scan_reduce<<<nodeBlocks, 256, 0, stream>>>(counts, blockSums, N_NODES);
    scan_tops<<<1, 256, 0, stream>>>(blockSums, blockOffs, &row_ptr[N_NODES], nodeBlocks);
    scan_final<<<nodeBlocks, 256, 0, stream>>>(counts, blockOffs, row_ptr, cursor, N_NODES);
    scatter_kernel<<<edgeBlocks, 256, 0, stream>>>(edge_src, edge_dst, edge_weight,
                                                   cursor, pairs, N_EDGES);

    // weight prep
    transpose_to_bf16<<<(NFEAT * NHID + 255) / 256, 256, 0, stream>>>(W1, Wt1, NFEAT, NHID);
    transpose_to_bf16<<<(NHID * NHID + 255) / 256, 256, 0, stream>>>(Wh, Wth, NHID, NHID);

    // Layer 1
    gemm_mfma_n128<false><<<waveBlocks, 256, 0, stream>>>(x, Wt1, tb, N_NODES, NFEAT);
    spmm_bias_relu_bf16<<<spmmBlocks, 256, 0, stream>>>(tb, row_ptr, pairs, b1, hb);

    // Layer 2
    gemm_mfma_n128<true><<<waveBlocks, 256, 0, stream>>>(hb, Wth, tb, N_NODES, NHID);
    spmm_bias_relu_bf16<<<spmmBlocks, 256, 0, stream>>>(tb, row_ptr, pairs, bh, hb);

    // Layer 3
    gemm_n40_bf16A<<<gemmBlocks, 256, 0, stream>>>(hb, W2, t3, N_NODES);
    spmm_logsoftmax<<<spmmBlocks, 256, 0, stream>>>(t3, row_ptr, pairs, b2, out);
}

// Round 4
// 511.559 us; speedup vs baseline: 2.0112x; 1.2373x over previous
//
#include <hip/hip_runtime.h>
#include <hip/hip_bf16.h>
#include <math.h>

#define N_NODES 50000
#define N_EDGES 1600000
#define NFEAT 512
#define NHID 128
#define NCLASS 40

#define NBUCKETS 196      // ceil(N_NODES / 256)
#define BUCKET_CAP 16384  // avg fill ~8163, sigma ~90 -> 16384 is untouchable margin

typedef __attribute__((ext_vector_type(8))) short bf16x8;
typedef __attribute__((ext_vector_type(4))) float f32x4;

static __device__ __forceinline__ float asfloat_u32(unsigned int u) {
    union { unsigned int u; float f; } c;
    c.u = u;
    return c.f;
}
static __device__ __forceinline__ unsigned int asu32_f(float f) {
    union { float f; unsigned int u; } c;
    c.f = f;
    return c.u;
}
static __device__ __forceinline__ unsigned short f2bf(float f) {
    union { float f; unsigned int u; } c;
    c.f = f;
    unsigned int r = c.u + 0x7FFFu + ((c.u >> 16) & 1u);  // RTN-even
    return (unsigned short)(r >> 16);
}

// ---------------- CSR build (two-pass bucket binning) ----------------

__global__ __launch_bounds__(256) void zero_cursors(int* bucketCursor) {
    int i = threadIdx.x;
    if (i < NBUCKETS) bucketCursor[i] = i * BUCKET_CAP;
}

// Pass 1: bin edges by dst>>8 into capacity-laid-out buckets.
// Record: x = src | (dst&255)<<16 ; y = weight bits.
__global__ __launch_bounds__(256) void bin_kernel(const int* __restrict__ src,
                                                  const int* __restrict__ dst,
                                                  const float* __restrict__ w,
                                                  int* __restrict__ bucketCursor,
                                                  uint2* __restrict__ binned, int n) {
    __shared__ int hist[NBUCKETS];
    __shared__ int cur[NBUCKETS];
    const int tid = threadIdx.x;
    const int base = blockIdx.x * 4096;
    if (tid < NBUCKETS) hist[tid] = 0;
    __syncthreads();
#pragma unroll
    for (int r = 0; r < 16; ++r) {
        int e = base + r * 256 + tid;
        if (e < n) atomicAdd(&hist[dst[e] >> 8], 1);
    }
    __syncthreads();
    if (tid < NBUCKETS && hist[tid] > 0)
        cur[tid] = atomicAdd(&bucketCursor[tid], hist[tid]);
    __syncthreads();
#pragma unroll
    for (int r = 0; r < 16; ++r) {
        int e = base + r * 256 + tid;
        if (e < n) {
            int d = dst[e];
            int pos = atomicAdd(&cur[d >> 8], 1);
            uint2 rec;
            rec.x = (unsigned int)src[e] | ((unsigned int)(d & 255) << 16);
            rec.y = asu32_f(w[e]);
            binned[pos] = rec;
        }
    }
}

// Scan bucket fill counts -> bucketStart[0..NBUCKETS]
__global__ __launch_bounds__(256) void scan_buckets(const int* __restrict__ bucketCursor,
                                                    int* __restrict__ bucketStart) {
    __shared__ int s[256];
    const int tid = threadIdx.x;
    int c = (tid < NBUCKETS) ? (bucketCursor[tid] - tid * BUCKET_CAP) : 0;
    s[tid] = c;
    __syncthreads();
    for (int off = 1; off < 256; off <<= 1) {
        int t = (tid >= off) ? s[tid - off] : 0;
        __syncthreads();
        s[tid] += t;
        __syncthreads();
    }
    if (tid < NBUCKETS) bucketStart[tid] = s[tid] - c;
    if (tid == NBUCKETS - 1) bucketStart[NBUCKETS] = s[tid];
}

// Pass 2: one workgroup per bucket. Node-level hist + LDS scan -> row_ptr,
// then scatter into final CSR (writes confined to this bucket's ~65KB window).
__global__ __launch_bounds__(256) void build_csr(const uint2* __restrict__ binned,
                                                 const int* __restrict__ bucketStart,
                                                 uint2* __restrict__ pairs,
                                                 int* __restrict__ row_ptr) {
    __shared__ int hist[256];
    __shared__ int sc[256];
    __shared__ int cur[256];
    const int b = blockIdx.x;
    const int tid = threadIdx.x;
    const int segStart = bucketStart[b];
    const int cnt = bucketStart[b + 1] - segStart;
    const uint2* seg = binned + (size_t)b * BUCKET_CAP;

    hist[tid] = 0;
    __syncthreads();
    for (int i = tid; i < cnt; i += 256)
        atomicAdd(&hist[seg[i].x >> 16], 1);
    __syncthreads();
    int v = hist[tid];
    sc[tid] = v;
    __syncthreads();
    for (int off = 1; off < 256; off <<= 1) {
        int t = (tid >= off) ? sc[tid - off] : 0;
        __syncthreads();
        sc[tid] += t;
        __syncthreads();
    }
    int excl = sc[tid] - v;
    int node = b * 256 + tid;
    if (node < N_NODES) row_ptr[node] = segStart + excl;
    if (b == NBUCKETS - 1 && tid == 0) row_ptr[N_NODES] = bucketStart[NBUCKETS];
    cur[tid] = segStart + excl;
    __syncthreads();
    for (int i = tid; i < cnt; i += 256) {
        uint2 p = seg[i];
        int pos = atomicAdd(&cur[p.x >> 16], 1);
        uint2 rec;
        rec.x = p.x & 0xFFFFu;
        rec.y = p.y;
        pairs[pos] = rec;
    }
}

// ---------------- weight transpose + bf16 convert ----------------
__global__ __launch_bounds__(256) void transpose_to_bf16(const float* __restrict__ W,
                                                         unsigned short* __restrict__ Wt,
                                                         int K, int N) {
    int idx = blockIdx.x * 256 + threadIdx.x;
    if (idx < K * N) {
        int k = idx / N;
        int n = idx - k * N;
        Wt[(size_t)n * K + k] = f2bf(W[idx]);
    }
}

// ---------------- MFMA GEMM, N=128 ----------------
template <bool A_IS_BF16>
__global__ __launch_bounds__(256) void gemm_mfma_n128(const void* __restrict__ Ap,
                                                      const unsigned short* __restrict__ Wt,
                                                      unsigned short* __restrict__ C,
                                                      const int M, const int K) {
    const int gwave = (blockIdx.x * 256 + threadIdx.x) >> 6;
    const int m0 = gwave * 16;
    if (m0 >= M) return;
    const int lane = threadIdx.x & 63;
    const int ln = lane & 15;
    const int quad = lane >> 4;

    f32x4 acc[8];
#pragma unroll
    for (int t = 0; t < 8; ++t) acc[t] = (f32x4){0.f, 0.f, 0.f, 0.f};

    const int row = m0 + ln;
    for (int kc = 0; kc < K; kc += 32) {
        bf16x8 a;
        if (A_IS_BF16) {
            a = *(const bf16x8*)((const unsigned short*)Ap + (size_t)row * K + kc + quad * 8);
        } else {
            const float* Af = (const float*)Ap + (size_t)row * K + kc + quad * 8;
            float4 f0 = *(const float4*)(Af);
            float4 f1 = *(const float4*)(Af + 4);
            a[0] = (short)f2bf(f0.x); a[1] = (short)f2bf(f0.y);
            a[2] = (short)f2bf(f0.z); a[3] = (short)f2bf(f0.w);
            a[4] = (short)f2bf(f1.x); a[5] = (short)f2bf(f1.y);
            a[6] = (short)f2bf(f1.z); a[7] = (short)f2bf(f1.w);
        }
#pragma unroll
        for (int t = 0; t < 8; ++t) {
            bf16x8 b = *(const bf16x8*)(Wt + (size_t)(t * 16 + ln) * K + kc + quad * 8);
            acc[t] = __builtin_amdgcn_mfma_f32_16x16x32_bf16(a, b, acc[t], 0, 0, 0);
        }
    }

#pragma unroll
    for (int t = 0; t < 8; ++t)
#pragma unroll
        for (int r = 0; r < 4; ++r)
            C[(size_t)(m0 + quad * 4 + r) * 128 + t * 16 + ln] = f2bf(acc[t][r]);
}

// ---------------- GEMM, N=40, K=128, A in bf16 ----------------
__global__ __launch_bounds__(256) void gemm_n40_bf16A(const unsigned short* __restrict__ A,
                                                      const float* __restrict__ Bm,
                                                      float* __restrict__ C, int M) {
    __shared__ float As[64][132];
    __shared__ float Bs[128 * 40];
    const int tid = threadIdx.x;
    const int tr = tid >> 2;
    const int tc = tid & 3;
    const int row0 = blockIdx.x * 64;

#pragma unroll
    for (int q = tid; q < 2048; q += 256) {
        int r = q >> 5;
        int c = (q & 31) << 2;
        int row = row0 + r;
        uint2 u = make_uint2(0u, 0u);
        if (row < M) u = *(const uint2*)(A + (size_t)row * 128 + c);
        As[r][c + 0] = asfloat_u32(u.x << 16);
        As[r][c + 1] = asfloat_u32(u.x & 0xFFFF0000u);
        As[r][c + 2] = asfloat_u32(u.y << 16);
        As[r][c + 3] = asfloat_u32(u.y & 0xFFFF0000u);
    }
    for (int q = tid; q < 128 * 40; q += 256) Bs[q] = Bm[q];
    __syncthreads();

    float acc[10];
#pragma unroll
    for (int j = 0; j < 10; ++j) acc[j] = 0.f;

    for (int k = 0; k < 128; ++k) {
        float a = As[tr][k];
#pragma unroll
        for (int j = 0; j < 10; ++j) acc[j] += a * Bs[k * 40 + tc * 10 + j];
    }

    int row = row0 + tr;
    if (row < M) {
#pragma unroll
        for (int j = 0; j < 10; ++j) C[(size_t)row * 40 + tc * 10 + j] = acc[j];
    }
}

// ---------------- SpMM (CSR gather, bf16 rows) + bias + ReLU, feat=128 ----------------
__global__ __launch_bounds__(256) void spmm_bias_relu_bf16(const unsigned short* __restrict__ t,
                                                           const int* __restrict__ row_ptr,
                                                           const uint2* __restrict__ pairs,
                                                           const float* __restrict__ bias,
                                                           unsigned short* __restrict__ out) {
    const int node = blockIdx.x * 4 + (threadIdx.x >> 6);
    const int lane = threadIdx.x & 63;
    const int e0 = row_ptr[node];
    const int e1 = row_ptr[node + 1];
    float ax = 0.f, ay = 0.f;
    int e = e0;
    for (; e + 8 <= e1; e += 8) {
        uint2 p0 = pairs[e],     p1 = pairs[e + 1], p2 = pairs[e + 2], p3 = pairs[e + 3];
        uint2 p4 = pairs[e + 4], p5 = pairs[e + 5], p6 = pairs[e + 6], p7 = pairs[e + 7];
        unsigned int v0 = *(const unsigned int*)(t + (size_t)p0.x * 128 + lane * 2);
        unsigned int v1 = *(const unsigned int*)(t + (size_t)p1.x * 128 + lane * 2);
        unsigned int v2 = *(const unsigned int*)(t + (size_t)p2.x * 128 + lane * 2);
        unsigned int v3 = *(const unsigned int*)(t + (size_t)p3.x * 128 + lane * 2);
        unsigned int v4 = *(const unsigned int*)(t + (size_t)p4.x * 128 + lane * 2);
        unsigned int v5 = *(const unsigned int*)(t + (size_t)p5.x * 128 + lane * 2);
        unsigned int v6 = *(const unsigned int*)(t + (size_t)p6.x * 128 + lane * 2);
        unsigned int v7 = *(const unsigned int*)(t + (size_t)p7.x * 128 + lane * 2);
        float w0 = asfloat_u32(p0.y), w1 = asfloat_u32(p1.y);
        float w2 = asfloat_u32(p2.y), w3 = asfloat_u32(p3.y);
        float w4 = asfloat_u32(p4.y), w5 = asfloat_u32(p5.y);
        float w6 = asfloat_u32(p6.y), w7 = asfloat_u32(p7.y);
        ax += w0 * asfloat_u32(v0 << 16); ay += w0 * asfloat_u32(v0 & 0xFFFF0000u);
        ax += w1 * asfloat_u32(v1 << 16); ay += w1 * asfloat_u32(v1 & 0xFFFF0000u);
        ax += w2 * asfloat_u32(v2 << 16); ay += w2 * asfloat_u32(v2 & 0xFFFF0000u);
        ax += w3 * asfloat_u32(v3 << 16); ay += w3 * asfloat_u32(v3 & 0xFFFF0000u);
        ax += w4 * asfloat_u32(v4 << 16); ay += w4 * asfloat_u32(v4 & 0xFFFF0000u);
        ax += w5 * asfloat_u32(v5 << 16); ay += w5 * asfloat_u32(v5 & 0xFFFF0000u);
        ax += w6 * asfloat_u32(v6 << 16); ay += w6 * asfloat_u32(v6 & 0xFFFF0000u);
        ax += w7 * asfloat_u32(v7 << 16); ay += w7 * asfloat_u32(v7 & 0xFFFF0000u);
    }
    for (; e < e1; ++e) {
        uint2 p = pairs[e];
        float w = asfloat_u32(p.y);
        unsigned int v = *(const unsigned int*)(t + (size_t)p.x * 128 + lane * 2);
        ax += w * asfloat_u32(v << 16);
        ay += w * asfloat_u32(v & 0xFFFF0000u);
    }
    float2 b = *(const float2*)&bias[lane * 2];
    ax = fmaxf(ax + b.x, 0.f);
    ay = fmaxf(ay + b.y, 0.f);
    unsigned int packed = ((unsigned int)f2bf(ax)) | (((unsigned int)f2bf(ay)) << 16);
    *(unsigned int*)(out + (size_t)node * 128 + lane * 2) = packed;
}

// ---------------- SpMM feat=40 (fp32) + bias + log_softmax ----------------
__global__ __launch_bounds__(256) void spmm_logsoftmax(const float* __restrict__ t,
                                                       const int* __restrict__ row_ptr,
                                                       const uint2* __restrict__ pairs,
                                                       const float* __restrict__ bias,
                                                       float* __restrict__ out) {
    const int node = blockIdx.x * 4 + (threadIdx.x >> 6);
    const int lane = threadIdx.x & 63;
    const int e0 = row_ptr[node];
    const int e1 = row_ptr[node + 1];
    const bool act = lane < NCLASS;
    float acc = 0.f;
    int e = e0;
    for (; e + 4 <= e1; e += 4) {
        uint2 p0 = pairs[e], p1 = pairs[e + 1], p2 = pairs[e + 2], p3 = pairs[e + 3];
        if (act) {
            float v0 = t[(size_t)p0.x * NCLASS + lane];
            float v1 = t[(size_t)p1.x * NCLASS + lane];
            float v2 = t[(size_t)p2.x * NCLASS + lane];
            float v3 = t[(size_t)p3.x * NCLASS + lane];
            acc += asfloat_u32(p0.y) * v0 + asfloat_u32(p1.y) * v1 +
                   asfloat_u32(p2.y) * v2 + asfloat_u32(p3.y) * v3;
        }
    }
    for (; e < e1; ++e) {
        uint2 p = pairs[e];
        if (act) acc += asfloat_u32(p.y) * t[(size_t)p.x * NCLASS + lane];
    }
    float logit = act ? (acc + bias[lane]) : -INFINITY;
    float m = logit;
#pragma unroll
    for (int off = 32; off; off >>= 1) m = fmaxf(m, __shfl_xor(m, off));
    float ex = act ? __expf(logit - m) : 0.f;
    float ssum = ex;
#pragma unroll
    for (int off = 32; off; off >>= 1) ssum += __shfl_xor(ssum, off);
    if (act) out[(size_t)node * NCLASS + lane] = logit - m - __logf(ssum);
}

// ---------------- launch ----------------

extern "C" void kernel_launch(void* const* d_in, const int* in_sizes, int n_in,
                              void* d_out, int out_size, void* d_ws, size_t ws_size,
                              hipStream_t stream) {
    const float* x = (const float*)d_in[0];
    const int* edge_src = (const int*)d_in[1];
    const int* edge_dst = (const int*)d_in[2];
    const float* edge_weight = (const float*)d_in[3];
    const float* W1 = (const float*)d_in[4];
    const float* b1 = (const float*)d_in[5];
    const float* Wh = (const float*)d_in[6];
    const float* bh = (const float*)d_in[7];
    const float* W2 = (const float*)d_in[8];
    const float* b2 = (const float*)d_in[9];
    float* out = (float*)d_out;

    size_t off = 0;
    auto carve = [&](size_t bytes) {
        void* p = (char*)d_ws + off;
        off += (bytes + 511) & ~(size_t)511;
        return p;
    };
    unsigned short* tb = (unsigned short*)carve((size_t)N_NODES * 128 * 2);
    unsigned short* hb = (unsigned short*)carve((size_t)N_NODES * 128 * 2);
    float* t3 = (float*)carve((size_t)N_NODES * NCLASS * 4);
    unsigned short* Wt1 = (unsigned short*)carve((size_t)NFEAT * NHID * 2);
    unsigned short* Wth = (unsigned short*)carve((size_t)NHID * NHID * 2);
    int* row_ptr = (int*)carve((size_t)(N_NODES + 4) * 4);
    int* bucketCursor = (int*)carve((size_t)NBUCKETS * 4);
    int* bucketStart = (int*)carve((size_t)(NBUCKETS + 1) * 4);
    uint2* binned = (uint2*)carve((size_t)NBUCKETS * BUCKET_CAP * 8);
    uint2* pairs = (uint2*)carve((size_t)N_EDGES * 8);
    (void)ws_size; (void)n_in; (void)in_sizes; (void)out_size;

    const int binBlocks = (N_EDGES + 4095) / 4096;    // 391
    const int spmmBlocks = N_NODES / 4;               // 12500
    const int waveBlocks = ((N_NODES / 16) + 3) / 4;  // 782
    const int gemmBlocks = (N_NODES + 63) / 64;       // 782

    // CSR build (two-pass binning)
    zero_cursors<<<1, 256, 0, stream>>>(bucketCursor);
    bin_kernel<<<binBlocks, 256, 0, stream>>>(edge_src, edge_dst, edge_weight,
                                              bucketCursor, binned, N_EDGES);
    scan_buckets<<<1, 256, 0, stream>>>(bucketCursor, bucketStart);
    build_csr<<<NBUCKETS, 256, 0, stream>>>(binned, bucketStart, pairs, row_ptr);

    // weight prep
    transpose_to_bf16<<<(NFEAT * NHID + 255) / 256, 256, 0, stream>>>(W1, Wt1, NFEAT, NHID);
    transpose_to_bf16<<<(NHID * NHID + 255) / 256, 256, 0, stream>>>(Wh, Wth, NHID, NHID);

    // Layer 1
    gemm_mfma_n128<false><<<waveBlocks, 256, 0, stream>>>(x, Wt1, tb, N_NODES, NFEAT);
    spmm_bias_relu_bf16<<<spmmBlocks, 256, 0, stream>>>(tb, row_ptr, pairs, b1, hb);

    // Layer 2
    gemm_mfma_n128<true><<<waveBlocks, 256, 0, stream>>>(hb, Wth, tb, N_NODES, NHID);
    spmm_bias_relu_bf16<<<spmmBlocks, 256, 0, stream>>>(tb, row_ptr, pairs, bh, hb);

    // Layer 3
    gemm_n40_bf16A<<<gemmBlocks, 256, 0, stream>>>(hb, W2, t3, N_NODES);
    spmm_logsoftmax<<<spmmBlocks, 256, 0, stream>>>(t3, row_ptr, pairs, b2, out);
}

// Round 5
// 466.749 us; speedup vs baseline: 2.2043x; 1.0960x over previous
//
#include <hip/hip_runtime.h>
#include <hip/hip_bf16.h>
#include <math.h>

#define N_NODES 50000
#define N_EDGES 1600000
#define NFEAT 512
#define NHID 128
#define NCLASS 40

#define NBUCKETS 196      // ceil(N_NODES / 256)
#define BUCKET_CAP 16384  // avg fill ~8163 -> huge margin

typedef __attribute__((ext_vector_type(8))) short bf16x8;
typedef __attribute__((ext_vector_type(4))) float f32x4;

static __device__ __forceinline__ float asfloat_u32(unsigned int u) {
    union { unsigned int u; float f; } c;
    c.u = u;
    return c.f;
}
static __device__ __forceinline__ unsigned int asu32_f(float f) {
    union { float f; unsigned int u; } c;
    c.f = f;
    return c.u;
}
static __device__ __forceinline__ unsigned short f2bf(float f) {
    union { float f; unsigned int u; } c;
    c.f = f;
    unsigned int r = c.u + 0x7FFFu + ((c.u >> 16) & 1u);  // RTN-even
    return (unsigned short)(r >> 16);
}

// ---------------- CSR build (two-pass bucket binning) ----------------

__global__ __launch_bounds__(256) void zero_cursors(int* bucketCursor) {
    int i = threadIdx.x;
    if (i < NBUCKETS) bucketCursor[i] = i * BUCKET_CAP;
}

__global__ __launch_bounds__(256) void bin_kernel(const int* __restrict__ src,
                                                  const int* __restrict__ dst,
                                                  const float* __restrict__ w,
                                                  int* __restrict__ bucketCursor,
                                                  uint2* __restrict__ binned, int n) {
    __shared__ int hist[NBUCKETS];
    __shared__ int cur[NBUCKETS];
    const int tid = threadIdx.x;
    const int base = blockIdx.x * 4096;
    if (tid < NBUCKETS) hist[tid] = 0;
    __syncthreads();
#pragma unroll
    for (int r = 0; r < 16; ++r) {
        int e = base + r * 256 + tid;
        if (e < n) atomicAdd(&hist[dst[e] >> 8], 1);
    }
    __syncthreads();
    if (tid < NBUCKETS && hist[tid] > 0)
        cur[tid] = atomicAdd(&bucketCursor[tid], hist[tid]);
    __syncthreads();
#pragma unroll
    for (int r = 0; r < 16; ++r) {
        int e = base + r * 256 + tid;
        if (e < n) {
            int d = dst[e];
            int pos = atomicAdd(&cur[d >> 8], 1);
            uint2 rec;
            rec.x = (unsigned int)src[e] | ((unsigned int)(d & 255) << 16);
            rec.y = asu32_f(w[e]);
            binned[pos] = rec;
        }
    }
}

__global__ __launch_bounds__(256) void scan_buckets(const int* __restrict__ bucketCursor,
                                                    int* __restrict__ bucketStart) {
    __shared__ int s[256];
    const int tid = threadIdx.x;
    int c = (tid < NBUCKETS) ? (bucketCursor[tid] - tid * BUCKET_CAP) : 0;
    s[tid] = c;
    __syncthreads();
    for (int off = 1; off < 256; off <<= 1) {
        int t = (tid >= off) ? s[tid - off] : 0;
        __syncthreads();
        s[tid] += t;
        __syncthreads();
    }
    if (tid < NBUCKETS) bucketStart[tid] = s[tid] - c;
    if (tid == NBUCKETS - 1) bucketStart[NBUCKETS] = s[tid];
}

__global__ __launch_bounds__(256) void build_csr(const uint2* __restrict__ binned,
                                                 const int* __restrict__ bucketStart,
                                                 uint2* __restrict__ pairs,
                                                 int* __restrict__ row_ptr) {
    __shared__ int hist[256];
    __shared__ int sc[256];
    __shared__ int cur[256];
    const int b = blockIdx.x;
    const int tid = threadIdx.x;
    const int segStart = bucketStart[b];
    const int cnt = bucketStart[b + 1] - segStart;
    const uint2* seg = binned + (size_t)b * BUCKET_CAP;

    hist[tid] = 0;
    __syncthreads();
    for (int i = tid; i < cnt; i += 256)
        atomicAdd(&hist[seg[i].x >> 16], 1);
    __syncthreads();
    int v = hist[tid];
    sc[tid] = v;
    __syncthreads();
    for (int off = 1; off < 256; off <<= 1) {
        int t = (tid >= off) ? sc[tid - off] : 0;
        __syncthreads();
        sc[tid] += t;
        __syncthreads();
    }
    int excl = sc[tid] - v;
    int node = b * 256 + tid;
    if (node < N_NODES) row_ptr[node] = segStart + excl;
    if (b == NBUCKETS - 1 && tid == 0) row_ptr[N_NODES] = bucketStart[NBUCKETS];
    cur[tid] = segStart + excl;
    __syncthreads();
    for (int i = tid; i < cnt; i += 256) {
        uint2 p = seg[i];
        int pos = atomicAdd(&cur[p.x >> 16], 1);
        uint2 rec;
        rec.x = p.x & 0xFFFFu;
        rec.y = p.y;
        pairs[pos] = rec;
    }
}

// ---------------- weight transpose + bf16 convert ----------------
__global__ __launch_bounds__(256) void transpose_to_bf16(const float* __restrict__ W,
                                                         unsigned short* __restrict__ Wt,
                                                         int K, int N) {
    int idx = blockIdx.x * 256 + threadIdx.x;
    if (idx < K * N) {
        int k = idx / N;
        int n = idx - k * N;
        Wt[(size_t)n * K + k] = f2bf(W[idx]);
    }
}

// ---------------- LDS-tiled MFMA GEMM, N=128 ----------------
// C[M x 128](bf16) = A[M x K] @ Wt^T ; Wt is [128][K] bf16 (pre-transposed B).
// Block: 256 thr (4 waves), tile 128(M) x 128(N), BK=32. Each wave: 32 rows.
// LDS rows padded to 40 bf16 (80B stride -> <=2-way bank aliasing, free).
// Layouts (m89/m91-verified): A-frag A[m=ln][k=quad*8+j]; B-frag B[k][n=ln]=Wt[n][k];
// C/D row=quad*4+reg, col=ln.
#define LDP 40
template <bool A_IS_BF16>
__global__ __launch_bounds__(256) void gemm_tile_n128(const void* __restrict__ Ap,
                                                      const unsigned short* __restrict__ Wt,
                                                      unsigned short* __restrict__ C,
                                                      const int M, const int K) {
    __shared__ unsigned short As[128 * LDP];
    __shared__ unsigned short Bs[128 * LDP];
    const int tid = threadIdx.x;
    const int wave = tid >> 6;
    const int lane = tid & 63;
    const int ln = lane & 15;
    const int quad = lane >> 4;
    const int row0 = blockIdx.x * 128;

    const int sr = tid >> 1;       // staging row 0..127
    const int half = tid & 1;      // staging k-half (16 elems each)
    const bool srOk = (row0 + sr) < M;

    f32x4 acc0[8], acc1[8];
#pragma unroll
    for (int t = 0; t < 8; ++t) {
        acc0[t] = (f32x4){0.f, 0.f, 0.f, 0.f};
        acc1[t] = (f32x4){0.f, 0.f, 0.f, 0.f};
    }

    const int wrow = wave * 32;

    for (int kc = 0; kc < K; kc += 32) {
        // ---- stage A (128x32 bf16) ----
        bf16x8 va0, va1;
        if (A_IS_BF16) {
            if (srOk) {
                const unsigned short* Ab =
                    (const unsigned short*)Ap + (size_t)(row0 + sr) * K + kc + half * 16;
                va0 = *(const bf16x8*)Ab;
                va1 = *(const bf16x8*)(Ab + 8);
            } else {
#pragma unroll
                for (int i = 0; i < 8; ++i) { va0[i] = 0; va1[i] = 0; }
            }
        } else {
            if (srOk) {
                const float* Af = (const float*)Ap + (size_t)(row0 + sr) * K + kc + half * 16;
                float4 f0 = *(const float4*)(Af);
                float4 f1 = *(const float4*)(Af + 4);
                float4 f2 = *(const float4*)(Af + 8);
                float4 f3 = *(const float4*)(Af + 12);
                va0[0] = (short)f2bf(f0.x); va0[1] = (short)f2bf(f0.y);
                va0[2] = (short)f2bf(f0.z); va0[3] = (short)f2bf(f0.w);
                va0[4] = (short)f2bf(f1.x); va0[5] = (short)f2bf(f1.y);
                va0[6] = (short)f2bf(f1.z); va0[7] = (short)f2bf(f1.w);
                va1[0] = (short)f2bf(f2.x); va1[1] = (short)f2bf(f2.y);
                va1[2] = (short)f2bf(f2.z); va1[3] = (short)f2bf(f2.w);
                va1[4] = (short)f2bf(f3.x); va1[5] = (short)f2bf(f3.y);
                va1[6] = (short)f2bf(f3.z); va1[7] = (short)f2bf(f3.w);
            } else {
#pragma unroll
                for (int i = 0; i < 8; ++i) { va0[i] = 0; va1[i] = 0; }
            }
        }
        // ---- stage B (128x32 bf16) ----
        const unsigned short* Bg = Wt + (size_t)sr * K + kc + half * 16;
        bf16x8 vb0 = *(const bf16x8*)Bg;
        bf16x8 vb1 = *(const bf16x8*)(Bg + 8);

        *(bf16x8*)&As[sr * LDP + half * 16] = va0;
        *(bf16x8*)&As[sr * LDP + half * 16 + 8] = va1;
        *(bf16x8*)&Bs[sr * LDP + half * 16] = vb0;
        *(bf16x8*)&Bs[sr * LDP + half * 16 + 8] = vb1;
        __syncthreads();

        // ---- compute: 2 row-tiles x 8 col-tiles ----
        bf16x8 a0 = *(const bf16x8*)&As[(wrow + ln) * LDP + quad * 8];
        bf16x8 a1 = *(const bf16x8*)&As[(wrow + 16 + ln) * LDP + quad * 8];
#pragma unroll
        for (int t = 0; t < 8; ++t) {
            bf16x8 b = *(const bf16x8*)&Bs[(t * 16 + ln) * LDP + quad * 8];
            acc0[t] = __builtin_amdgcn_mfma_f32_16x16x32_bf16(a0, b, acc0[t], 0, 0, 0);
            acc1[t] = __builtin_amdgcn_mfma_f32_16x16x32_bf16(a1, b, acc1[t], 0, 0, 0);
        }
        __syncthreads();
    }

#pragma unroll
    for (int t = 0; t < 8; ++t) {
#pragma unroll
        for (int r = 0; r < 4; ++r) {
            int row = row0 + wrow + quad * 4 + r;
            if (row < M) C[(size_t)row * 128 + t * 16 + ln] = f2bf(acc0[t][r]);
            row += 16;
            if (row < M) C[(size_t)row * 128 + t * 16 + ln] = f2bf(acc1[t][r]);
        }
    }
}

// ---------------- GEMM, N=40, K=128, A in bf16 ----------------
__global__ __launch_bounds__(256) void gemm_n40_bf16A(const unsigned short* __restrict__ A,
                                                      const float* __restrict__ Bm,
                                                      float* __restrict__ C, int M) {
    __shared__ float As[64][132];
    __shared__ float Bs[128 * 40];
    const int tid = threadIdx.x;
    const int tr = tid >> 2;
    const int tc = tid & 3;
    const int row0 = blockIdx.x * 64;

#pragma unroll
    for (int q = tid; q < 2048; q += 256) {
        int r = q >> 5;
        int c = (q & 31) << 2;
        int row = row0 + r;
        uint2 u = make_uint2(0u, 0u);
        if (row < M) u = *(const uint2*)(A + (size_t)row * 128 + c);
        As[r][c + 0] = asfloat_u32(u.x << 16);
        As[r][c + 1] = asfloat_u32(u.x & 0xFFFF0000u);
        As[r][c + 2] = asfloat_u32(u.y << 16);
        As[r][c + 3] = asfloat_u32(u.y & 0xFFFF0000u);
    }
    for (int q = tid; q < 128 * 40; q += 256) Bs[q] = Bm[q];
    __syncthreads();

    float acc[10];
#pragma unroll
    for (int j = 0; j < 10; ++j) acc[j] = 0.f;

    for (int k = 0; k < 128; ++k) {
        float a = As[tr][k];
#pragma unroll
        for (int j = 0; j < 10; ++j) acc[j] += a * Bs[k * 40 + tc * 10 + j];
    }

    int row = row0 + tr;
    if (row < M) {
#pragma unroll
        for (int j = 0; j < 10; ++j) C[(size_t)row * 40 + tc * 10 + j] = acc[j];
    }
}

// ---------------- SpMM (CSR gather, bf16 rows) + bias + ReLU, feat=128 ----------------
__global__ __launch_bounds__(256) void spmm_bias_relu_bf16(const unsigned short* __restrict__ t,
                                                           const int* __restrict__ row_ptr,
                                                           const uint2* __restrict__ pairs,
                                                           const float* __restrict__ bias,
                                                           unsigned short* __restrict__ out) {
    const int node = blockIdx.x * 4 + (threadIdx.x >> 6);
    const int lane = threadIdx.x & 63;
    const int e0 = row_ptr[node];
    const int e1 = row_ptr[node + 1];
    float ax = 0.f, ay = 0.f;
    int e = e0;
    for (; e + 8 <= e1; e += 8) {
        uint2 p0 = pairs[e],     p1 = pairs[e + 1], p2 = pairs[e + 2], p3 = pairs[e + 3];
        uint2 p4 = pairs[e + 4], p5 = pairs[e + 5], p6 = pairs[e + 6], p7 = pairs[e + 7];
        unsigned int v0 = *(const unsigned int*)(t + (size_t)p0.x * 128 + lane * 2);
        unsigned int v1 = *(const unsigned int*)(t + (size_t)p1.x * 128 + lane * 2);
        unsigned int v2 = *(const unsigned int*)(t + (size_t)p2.x * 128 + lane * 2);
        unsigned int v3 = *(const unsigned int*)(t + (size_t)p3.x * 128 + lane * 2);
        unsigned int v4 = *(const unsigned int*)(t + (size_t)p4.x * 128 + lane * 2);
        unsigned int v5 = *(const unsigned int*)(t + (size_t)p5.x * 128 + lane * 2);
        unsigned int v6 = *(const unsigned int*)(t + (size_t)p6.x * 128 + lane * 2);
        unsigned int v7 = *(const unsigned int*)(t + (size_t)p7.x * 128 + lane * 2);
        float w0 = asfloat_u32(p0.y), w1 = asfloat_u32(p1.y);
        float w2 = asfloat_u32(p2.y), w3 = asfloat_u32(p3.y);
        float w4 = asfloat_u32(p4.y), w5 = asfloat_u32(p5.y);
        float w6 = asfloat_u32(p6.y), w7 = asfloat_u32(p7.y);
        ax += w0 * asfloat_u32(v0 << 16); ay += w0 * asfloat_u32(v0 & 0xFFFF0000u);
        ax += w1 * asfloat_u32(v1 << 16); ay += w1 * asfloat_u32(v1 & 0xFFFF0000u);
        ax += w2 * asfloat_u32(v2 << 16); ay += w2 * asfloat_u32(v2 & 0xFFFF0000u);
        ax += w3 * asfloat_u32(v3 << 16); ay += w3 * asfloat_u32(v3 & 0xFFFF0000u);
        ax += w4 * asfloat_u32(v4 << 16); ay += w4 * asfloat_u32(v4 & 0xFFFF0000u);
        ax += w5 * asfloat_u32(v5 << 16); ay += w5 * asfloat_u32(v5 & 0xFFFF0000u);
        ax += w6 * asfloat_u32(v6 << 16); ay += w6 * asfloat_u32(v6 & 0xFFFF0000u);
        ax += w7 * asfloat_u32(v7 << 16); ay += w7 * asfloat_u32(v7 & 0xFFFF0000u);
    }
    for (; e < e1; ++e) {
        uint2 p = pairs[e];
        float w = asfloat_u32(p.y);
        unsigned int v = *(const unsigned int*)(t + (size_t)p.x * 128 + lane * 2);
        ax += w * asfloat_u32(v << 16);
        ay += w * asfloat_u32(v & 0xFFFF0000u);
    }
    float2 b = *(const float2*)&bias[lane * 2];
    ax = fmaxf(ax + b.x, 0.f);
    ay = fmaxf(ay + b.y, 0.f);
    unsigned int packed = ((unsigned int)f2bf(ax)) | (((unsigned int)f2bf(ay)) << 16);
    *(unsigned int*)(out + (size_t)node * 128 + lane * 2) = packed;
}

// ---------------- SpMM feat=40 (fp32) + bias + log_softmax ----------------
__global__ __launch_bounds__(256) void spmm_logsoftmax(const float* __restrict__ t,
                                                       const int* __restrict__ row_ptr,
                                                       const uint2* __restrict__ pairs,
                                                       const float* __restrict__ bias,
                                                       float* __restrict__ out) {
    const int node = blockIdx.x * 4 + (threadIdx.x >> 6);
    const int lane = threadIdx.x & 63;
    const int e0 = row_ptr[node];
    const int e1 = row_ptr[node + 1];
    const bool act = lane < NCLASS;
    float acc = 0.f;
    int e = e0;
    for (; e + 4 <= e1; e += 4) {
        uint2 p0 = pairs[e], p1 = pairs[e + 1], p2 = pairs[e + 2], p3 = pairs[e + 3];
        if (act) {
            float v0 = t[(size_t)p0.x * NCLASS + lane];
            float v1 = t[(size_t)p1.x * NCLASS + lane];
            float v2 = t[(size_t)p2.x * NCLASS + lane];
            float v3 = t[(size_t)p3.x * NCLASS + lane];
            acc += asfloat_u32(p0.y) * v0 + asfloat_u32(p1.y) * v1 +
                   asfloat_u32(p2.y) * v2 + asfloat_u32(p3.y) * v3;
        }
    }
    for (; e < e1; ++e) {
        uint2 p = pairs[e];
        if (act) acc += asfloat_u32(p.y) * t[(size_t)p.x * NCLASS + lane];
    }
    float logit = act ? (acc + bias[lane]) : -INFINITY;
    float m = logit;
#pragma unroll
    for (int off = 32; off; off >>= 1) m = fmaxf(m, __shfl_xor(m, off));
    float ex = act ? __expf(logit - m) : 0.f;
    float ssum = ex;
#pragma unroll
    for (int off = 32; off; off >>= 1) ssum += __shfl_xor(ssum, off);
    if (act) out[(size_t)node * NCLASS + lane] = logit - m - __logf(ssum);
}

// ---------------- launch ----------------

extern "C" void kernel_launch(void* const* d_in, const int* in_sizes, int n_in,
                              void* d_out, int out_size, void* d_ws, size_t ws_size,
                              hipStream_t stream) {
    const float* x = (const float*)d_in[0];
    const int* edge_src = (const int*)d_in[1];
    const int* edge_dst = (const int*)d_in[2];
    const float* edge_weight = (const float*)d_in[3];
    const float* W1 = (const float*)d_in[4];
    const float* b1 = (const float*)d_in[5];
    const float* Wh = (const float*)d_in[6];
    const float* bh = (const float*)d_in[7];
    const float* W2 = (const float*)d_in[8];
    const float* b2 = (const float*)d_in[9];
    float* out = (float*)d_out;

    size_t off = 0;
    auto carve = [&](size_t bytes) {
        void* p = (char*)d_ws + off;
        off += (bytes + 511) & ~(size_t)511;
        return p;
    };
    unsigned short* tb = (unsigned short*)carve((size_t)N_NODES * 128 * 2);
    unsigned short* hb = (unsigned short*)carve((size_t)N_NODES * 128 * 2);
    float* t3 = (float*)carve((size_t)N_NODES * NCLASS * 4);
    unsigned short* Wt1 = (unsigned short*)carve((size_t)NFEAT * NHID * 2);
    unsigned short* Wth = (unsigned short*)carve((size_t)NHID * NHID * 2);
    int* row_ptr = (int*)carve((size_t)(N_NODES + 4) * 4);
    int* bucketCursor = (int*)carve((size_t)NBUCKETS * 4);
    int* bucketStart = (int*)carve((size_t)(NBUCKETS + 1) * 4);
    uint2* binned = (uint2*)carve((size_t)NBUCKETS * BUCKET_CAP * 8);
    uint2* pairs = (uint2*)carve((size_t)N_EDGES * 8);
    (void)ws_size; (void)n_in; (void)in_sizes; (void)out_size;

    const int binBlocks = (N_EDGES + 4095) / 4096;     // 391
    const int spmmBlocks = N_NODES / 4;                // 12500
    const int tileBlocks = (N_NODES + 127) / 128;      // 391
    const int gemmBlocks = (N_NODES + 63) / 64;        // 782

    // CSR build (two-pass binning)
    zero_cursors<<<1, 256, 0, stream>>>(bucketCursor);
    bin_kernel<<<binBlocks, 256, 0, stream>>>(edge_src, edge_dst, edge_weight,
                                              bucketCursor, binned, N_EDGES);
    scan_buckets<<<1, 256, 0, stream>>>(bucketCursor, bucketStart);
    build_csr<<<NBUCKETS, 256, 0, stream>>>(binned, bucketStart, pairs, row_ptr);

    // weight prep
    transpose_to_bf16<<<(NFEAT * NHID + 255) / 256, 256, 0, stream>>>(W1, Wt1, NFEAT, NHID);
    transpose_to_bf16<<<(NHID * NHID + 255) / 256, 256, 0, stream>>>(Wh, Wth, NHID, NHID);

    // Layer 1
    gemm_tile_n128<false><<<tileBlocks, 256, 0, stream>>>(x, Wt1, tb, N_NODES, NFEAT);
    spmm_bias_relu_bf16<<<spmmBlocks, 256, 0, stream>>>(tb, row_ptr, pairs, b1, hb);

    // Layer 2
    gemm_tile_n128<true><<<tileBlocks, 256, 0, stream>>>(hb, Wth, tb, N_NODES, NHID);
    spmm_bias_relu_bf16<<<spmmBlocks, 256, 0, stream>>>(tb, row_ptr, pairs, bh, hb);

    // Layer 3
    gemm_n40_bf16A<<<gemmBlocks, 256, 0, stream>>>(hb, W2, t3, N_NODES);
    spmm_logsoftmax<<<spmmBlocks, 256, 0, stream>>>(t3, row_ptr, pairs, b2, out);
}

// Round 6
// 453.139 us; speedup vs baseline: 2.2705x; 1.0300x over previous
//
#include <hip/hip_runtime.h>
#include <hip/hip_bf16.h>
#include <math.h>

#define N_NODES 50000
#define N_EDGES 1600000
#define NFEAT 512
#define NHID 128
#define NCLASS 40

#define NBUCKETS 196      // ceil(N_NODES / 256)
#define BUCKET_CAP 16384  // avg fill ~8163 -> huge margin

typedef __attribute__((ext_vector_type(8))) short bf16x8;
typedef __attribute__((ext_vector_type(4))) float f32x4;

static __device__ __forceinline__ float asfloat_u32(unsigned int u) {
    union { unsigned int u; float f; } c;
    c.u = u;
    return c.f;
}
static __device__ __forceinline__ unsigned int asu32_f(float f) {
    union { float f; unsigned int u; } c;
    c.f = f;
    return c.u;
}
static __device__ __forceinline__ unsigned short f2bf(float f) {
    union { float f; unsigned int u; } c;
    c.f = f;
    unsigned int r = c.u + 0x7FFFu + ((c.u >> 16) & 1u);  // RTN-even
    return (unsigned short)(r >> 16);
}

// ---------------- CSR build (two-pass bucket binning) ----------------

__global__ __launch_bounds__(256) void zero_cursors(int* bucketCursor) {
    int i = threadIdx.x;
    if (i < NBUCKETS) bucketCursor[i] = i * BUCKET_CAP;
}

// Pass 1: bin by dst>>8. Record: x = src | (dst&255)<<16 ; y = fp32 weight bits.
__global__ __launch_bounds__(256) void bin_kernel(const int* __restrict__ src,
                                                  const int* __restrict__ dst,
                                                  const float* __restrict__ w,
                                                  int* __restrict__ bucketCursor,
                                                  uint2* __restrict__ binned, int n) {
    __shared__ int hist[NBUCKETS];
    __shared__ int cur[NBUCKETS];
    const int tid = threadIdx.x;
    const int base = blockIdx.x * 4096;
    if (tid < NBUCKETS) hist[tid] = 0;
    __syncthreads();
#pragma unroll
    for (int r = 0; r < 16; ++r) {
        int e = base + r * 256 + tid;
        if (e < n) atomicAdd(&hist[dst[e] >> 8], 1);
    }
    __syncthreads();
    if (tid < NBUCKETS && hist[tid] > 0)
        cur[tid] = atomicAdd(&bucketCursor[tid], hist[tid]);
    __syncthreads();
#pragma unroll
    for (int r = 0; r < 16; ++r) {
        int e = base + r * 256 + tid;
        if (e < n) {
            int d = dst[e];
            int pos = atomicAdd(&cur[d >> 8], 1);
            uint2 rec;
            rec.x = (unsigned int)src[e] | ((unsigned int)(d & 255) << 16);
            rec.y = asu32_f(w[e]);
            binned[pos] = rec;
        }
    }
}

__global__ __launch_bounds__(256) void scan_buckets(const int* __restrict__ bucketCursor,
                                                    int* __restrict__ bucketStart) {
    __shared__ int s[256];
    const int tid = threadIdx.x;
    int c = (tid < NBUCKETS) ? (bucketCursor[tid] - tid * BUCKET_CAP) : 0;
    s[tid] = c;
    __syncthreads();
    for (int off = 1; off < 256; off <<= 1) {
        int t = (tid >= off) ? s[tid - off] : 0;
        __syncthreads();
        s[tid] += t;
        __syncthreads();
    }
    if (tid < NBUCKETS) bucketStart[tid] = s[tid] - c;
    if (tid == NBUCKETS - 1) bucketStart[NBUCKETS] = s[tid];
}

// Pass 2: per-bucket node hist + scan -> row_ptr; scatter 4B records:
// pairs[pos] = src(16b) | bf16(weight)(16b high)
__global__ __launch_bounds__(256) void build_csr(const uint2* __restrict__ binned,
                                                 const int* __restrict__ bucketStart,
                                                 unsigned int* __restrict__ pairs,
                                                 int* __restrict__ row_ptr) {
    __shared__ int hist[256];
    __shared__ int sc[256];
    __shared__ int cur[256];
    const int b = blockIdx.x;
    const int tid = threadIdx.x;
    const int segStart = bucketStart[b];
    const int cnt = bucketStart[b + 1] - segStart;
    const uint2* seg = binned + (size_t)b * BUCKET_CAP;

    hist[tid] = 0;
    __syncthreads();
    for (int i = tid; i < cnt; i += 256)
        atomicAdd(&hist[seg[i].x >> 16], 1);
    __syncthreads();
    int v = hist[tid];
    sc[tid] = v;
    __syncthreads();
    for (int off = 1; off < 256; off <<= 1) {
        int t = (tid >= off) ? sc[tid - off] : 0;
        __syncthreads();
        sc[tid] += t;
        __syncthreads();
    }
    int excl = sc[tid] - v;
    int node = b * 256 + tid;
    if (node < N_NODES) row_ptr[node] = segStart + excl;
    if (b == NBUCKETS - 1 && tid == 0) row_ptr[N_NODES] = bucketStart[NBUCKETS];
    cur[tid] = segStart + excl;
    __syncthreads();
    for (int i = tid; i < cnt; i += 256) {
        uint2 p = seg[i];
        int pos = atomicAdd(&cur[p.x >> 16], 1);
        pairs[pos] = (p.x & 0xFFFFu) |
                     ((unsigned int)f2bf(asfloat_u32(p.y)) << 16);
    }
}

// ---------------- weight transpose + bf16 convert ----------------
__global__ __launch_bounds__(256) void transpose_to_bf16(const float* __restrict__ W,
                                                         unsigned short* __restrict__ Wt,
                                                         int K, int N) {
    int idx = blockIdx.x * 256 + threadIdx.x;
    if (idx < K * N) {
        int k = idx / N;
        int n = idx - k * N;
        Wt[(size_t)n * K + k] = f2bf(W[idx]);
    }
}

// ---------------- LDS-tiled MFMA GEMM, N=128 ----------------
#define LDP 40
template <bool A_IS_BF16>
__global__ __launch_bounds__(256) void gemm_tile_n128(const void* __restrict__ Ap,
                                                      const unsigned short* __restrict__ Wt,
                                                      unsigned short* __restrict__ C,
                                                      const int M, const int K) {
    __shared__ unsigned short As[128 * LDP];
    __shared__ unsigned short Bs[128 * LDP];
    const int tid = threadIdx.x;
    const int wave = tid >> 6;
    const int lane = tid & 63;
    const int ln = lane & 15;
    const int quad = lane >> 4;
    const int row0 = blockIdx.x * 128;

    const int sr = tid >> 1;
    const int half = tid & 1;
    const bool srOk = (row0 + sr) < M;

    f32x4 acc0[8], acc1[8];
#pragma unroll
    for (int t = 0; t < 8; ++t) {
        acc0[t] = (f32x4){0.f, 0.f, 0.f, 0.f};
        acc1[t] = (f32x4){0.f, 0.f, 0.f, 0.f};
    }

    const int wrow = wave * 32;

    for (int kc = 0; kc < K; kc += 32) {
        bf16x8 va0, va1;
        if (A_IS_BF16) {
            if (srOk) {
                const unsigned short* Ab =
                    (const unsigned short*)Ap + (size_t)(row0 + sr) * K + kc + half * 16;
                va0 = *(const bf16x8*)Ab;
                va1 = *(const bf16x8*)(Ab + 8);
            } else {
#pragma unroll
                for (int i = 0; i < 8; ++i) { va0[i] = 0; va1[i] = 0; }
            }
        } else {
            if (srOk) {
                const float* Af = (const float*)Ap + (size_t)(row0 + sr) * K + kc + half * 16;
                float4 f0 = *(const float4*)(Af);
                float4 f1 = *(const float4*)(Af + 4);
                float4 f2 = *(const float4*)(Af + 8);
                float4 f3 = *(const float4*)(Af + 12);
                va0[0] = (short)f2bf(f0.x); va0[1] = (short)f2bf(f0.y);
                va0[2] = (short)f2bf(f0.z); va0[3] = (short)f2bf(f0.w);
                va0[4] = (short)f2bf(f1.x); va0[5] = (short)f2bf(f1.y);
                va0[6] = (short)f2bf(f1.z); va0[7] = (short)f2bf(f1.w);
                va1[0] = (short)f2bf(f2.x); va1[1] = (short)f2bf(f2.y);
                va1[2] = (short)f2bf(f2.z); va1[3] = (short)f2bf(f2.w);
                va1[4] = (short)f2bf(f3.x); va1[5] = (short)f2bf(f3.y);
                va1[6] = (short)f2bf(f3.z); va1[7] = (short)f2bf(f3.w);
            } else {
#pragma unroll
                for (int i = 0; i < 8; ++i) { va0[i] = 0; va1[i] = 0; }
            }
        }
        const unsigned short* Bg = Wt + (size_t)sr * K + kc + half * 16;
        bf16x8 vb0 = *(const bf16x8*)Bg;
        bf16x8 vb1 = *(const bf16x8*)(Bg + 8);

        *(bf16x8*)&As[sr * LDP + half * 16] = va0;
        *(bf16x8*)&As[sr * LDP + half * 16 + 8] = va1;
        *(bf16x8*)&Bs[sr * LDP + half * 16] = vb0;
        *(bf16x8*)&Bs[sr * LDP + half * 16 + 8] = vb1;
        __syncthreads();

        bf16x8 a0 = *(const bf16x8*)&As[(wrow + ln) * LDP + quad * 8];
        bf16x8 a1 = *(const bf16x8*)&As[(wrow + 16 + ln) * LDP + quad * 8];
#pragma unroll
        for (int t = 0; t < 8; ++t) {
            bf16x8 b = *(const bf16x8*)&Bs[(t * 16 + ln) * LDP + quad * 8];
            acc0[t] = __builtin_amdgcn_mfma_f32_16x16x32_bf16(a0, b, acc0[t], 0, 0, 0);
            acc1[t] = __builtin_amdgcn_mfma_f32_16x16x32_bf16(a1, b, acc1[t], 0, 0, 0);
        }
        __syncthreads();
    }

#pragma unroll
    for (int t = 0; t < 8; ++t) {
#pragma unroll
        for (int r = 0; r < 4; ++r) {
            int row = row0 + wrow + quad * 4 + r;
            if (row < M) C[(size_t)row * 128 + t * 16 + ln] = f2bf(acc0[t][r]);
            row += 16;
            if (row < M) C[(size_t)row * 128 + t * 16 + ln] = f2bf(acc1[t][r]);
        }
    }
}

// ---------------- GEMM, N=40, K=128, A bf16 -> C bf16 ----------------
__global__ __launch_bounds__(256) void gemm_n40_bf16A(const unsigned short* __restrict__ A,
                                                      const float* __restrict__ Bm,
                                                      unsigned short* __restrict__ C, int M) {
    __shared__ float As[64][132];
    __shared__ float Bs[128 * 40];
    const int tid = threadIdx.x;
    const int tr = tid >> 2;
    const int tc = tid & 3;
    const int row0 = blockIdx.x * 64;

#pragma unroll
    for (int q = tid; q < 2048; q += 256) {
        int r = q >> 5;
        int c = (q & 31) << 2;
        int row = row0 + r;
        uint2 u = make_uint2(0u, 0u);
        if (row < M) u = *(const uint2*)(A + (size_t)row * 128 + c);
        As[r][c + 0] = asfloat_u32(u.x << 16);
        As[r][c + 1] = asfloat_u32(u.x & 0xFFFF0000u);
        As[r][c + 2] = asfloat_u32(u.y << 16);
        As[r][c + 3] = asfloat_u32(u.y & 0xFFFF0000u);
    }
    for (int q = tid; q < 128 * 40; q += 256) Bs[q] = Bm[q];
    __syncthreads();

    float acc[10];
#pragma unroll
    for (int j = 0; j < 10; ++j) acc[j] = 0.f;

    for (int k = 0; k < 128; ++k) {
        float a = As[tr][k];
#pragma unroll
        for (int j = 0; j < 10; ++j) acc[j] += a * Bs[k * 40 + tc * 10 + j];
    }

    int row = row0 + tr;
    if (row < M) {
#pragma unroll
        for (int j = 0; j < 10; ++j) C[(size_t)row * 40 + tc * 10 + j] = f2bf(acc[j]);
    }
}

// ---------------- SpMM (CSR gather, bf16 rows) + bias + ReLU, feat=128 ----------------
// 4B edge records: src = p & 0xFFFF, weight = bits(p & 0xFFFF0000)
__global__ __launch_bounds__(256) void spmm_bias_relu_bf16(const unsigned short* __restrict__ t,
                                                           const int* __restrict__ row_ptr,
                                                           const unsigned int* __restrict__ pairs,
                                                           const float* __restrict__ bias,
                                                           unsigned short* __restrict__ out) {
    const int node = blockIdx.x * 4 + (threadIdx.x >> 6);
    const int lane = threadIdx.x & 63;
    const int e0 = row_ptr[node];
    const int e1 = row_ptr[node + 1];
    float ax = 0.f, ay = 0.f;
    int e = e0;
    for (; e + 8 <= e1; e += 8) {
        unsigned int p0 = pairs[e],     p1 = pairs[e + 1], p2 = pairs[e + 2], p3 = pairs[e + 3];
        unsigned int p4 = pairs[e + 4], p5 = pairs[e + 5], p6 = pairs[e + 6], p7 = pairs[e + 7];
        unsigned int v0 = *(const unsigned int*)(t + (size_t)(p0 & 0xFFFFu) * 128 + lane * 2);
        unsigned int v1 = *(const unsigned int*)(t + (size_t)(p1 & 0xFFFFu) * 128 + lane * 2);
        unsigned int v2 = *(const unsigned int*)(t + (size_t)(p2 & 0xFFFFu) * 128 + lane * 2);
        unsigned int v3 = *(const unsigned int*)(t + (size_t)(p3 & 0xFFFFu) * 128 + lane * 2);
        unsigned int v4 = *(const unsigned int*)(t + (size_t)(p4 & 0xFFFFu) * 128 + lane * 2);
        unsigned int v5 = *(const unsigned int*)(t + (size_t)(p5 & 0xFFFFu) * 128 + lane * 2);
        unsigned int v6 = *(const unsigned int*)(t + (size_t)(p6 & 0xFFFFu) * 128 + lane * 2);
        unsigned int v7 = *(const unsigned int*)(t + (size_t)(p7 & 0xFFFFu) * 128 + lane * 2);
        float w0 = asfloat_u32(p0 & 0xFFFF0000u), w1 = asfloat_u32(p1 & 0xFFFF0000u);
        float w2 = asfloat_u32(p2 & 0xFFFF0000u), w3 = asfloat_u32(p3 & 0xFFFF0000u);
        float w4 = asfloat_u32(p4 & 0xFFFF0000u), w5 = asfloat_u32(p5 & 0xFFFF0000u);
        float w6 = asfloat_u32(p6 & 0xFFFF0000u), w7 = asfloat_u32(p7 & 0xFFFF0000u);
        ax += w0 * asfloat_u32(v0 << 16); ay += w0 * asfloat_u32(v0 & 0xFFFF0000u);
        ax += w1 * asfloat_u32(v1 << 16); ay += w1 * asfloat_u32(v1 & 0xFFFF0000u);
        ax += w2 * asfloat_u32(v2 << 16); ay += w2 * asfloat_u32(v2 & 0xFFFF0000u);
        ax += w3 * asfloat_u32(v3 << 16); ay += w3 * asfloat_u32(v3 & 0xFFFF0000u);
        ax += w4 * asfloat_u32(v4 << 16); ay += w4 * asfloat_u32(v4 & 0xFFFF0000u);
        ax += w5 * asfloat_u32(v5 << 16); ay += w5 * asfloat_u32(v5 & 0xFFFF0000u);
        ax += w6 * asfloat_u32(v6 << 16); ay += w6 * asfloat_u32(v6 & 0xFFFF0000u);
        ax += w7 * asfloat_u32(v7 << 16); ay += w7 * asfloat_u32(v7 & 0xFFFF0000u);
    }
    for (; e < e1; ++e) {
        unsigned int p = pairs[e];
        float w = asfloat_u32(p & 0xFFFF0000u);
        unsigned int v = *(const unsigned int*)(t + (size_t)(p & 0xFFFFu) * 128 + lane * 2);
        ax += w * asfloat_u32(v << 16);
        ay += w * asfloat_u32(v & 0xFFFF0000u);
    }
    float2 b = *(const float2*)&bias[lane * 2];
    ax = fmaxf(ax + b.x, 0.f);
    ay = fmaxf(ay + b.y, 0.f);
    unsigned int packed = ((unsigned int)f2bf(ax)) | (((unsigned int)f2bf(ay)) << 16);
    *(unsigned int*)(out + (size_t)node * 128 + lane * 2) = packed;
}

// ---------------- SpMM feat=40 (bf16 rows) + bias + log_softmax ----------------
__global__ __launch_bounds__(256) void spmm_logsoftmax(const unsigned short* __restrict__ t,
                                                       const int* __restrict__ row_ptr,
                                                       const unsigned int* __restrict__ pairs,
                                                       const float* __restrict__ bias,
                                                       float* __restrict__ out) {
    const int node = blockIdx.x * 4 + (threadIdx.x >> 6);
    const int lane = threadIdx.x & 63;
    const int e0 = row_ptr[node];
    const int e1 = row_ptr[node + 1];
    const bool act = lane < NCLASS;
    float acc = 0.f;
    int e = e0;
    for (; e + 4 <= e1; e += 4) {
        unsigned int p0 = pairs[e], p1 = pairs[e + 1], p2 = pairs[e + 2], p3 = pairs[e + 3];
        if (act) {
            float v0 = asfloat_u32((unsigned int)t[(size_t)(p0 & 0xFFFFu) * NCLASS + lane] << 16);
            float v1 = asfloat_u32((unsigned int)t[(size_t)(p1 & 0xFFFFu) * NCLASS + lane] << 16);
            float v2 = asfloat_u32((unsigned int)t[(size_t)(p2 & 0xFFFFu) * NCLASS + lane] << 16);
            float v3 = asfloat_u32((unsigned int)t[(size_t)(p3 & 0xFFFFu) * NCLASS + lane] << 16);
            acc += asfloat_u32(p0 & 0xFFFF0000u) * v0 + asfloat_u32(p1 & 0xFFFF0000u) * v1 +
                   asfloat_u32(p2 & 0xFFFF0000u) * v2 + asfloat_u32(p3 & 0xFFFF0000u) * v3;
        }
    }
    for (; e < e1; ++e) {
        unsigned int p = pairs[e];
        if (act)
            acc += asfloat_u32(p & 0xFFFF0000u) *
                   asfloat_u32((unsigned int)t[(size_t)(p & 0xFFFFu) * NCLASS + lane] << 16);
    }
    float logit = act ? (acc + bias[lane]) : -INFINITY;
    float m = logit;
#pragma unroll
    for (int off = 32; off; off >>= 1) m = fmaxf(m, __shfl_xor(m, off));
    float ex = act ? __expf(logit - m) : 0.f;
    float ssum = ex;
#pragma unroll
    for (int off = 32; off; off >>= 1) ssum += __shfl_xor(ssum, off);
    if (act) out[(size_t)node * NCLASS + lane] = logit - m - __logf(ssum);
}

// ---------------- launch ----------------

extern "C" void kernel_launch(void* const* d_in, const int* in_sizes, int n_in,
                              void* d_out, int out_size, void* d_ws, size_t ws_size,
                              hipStream_t stream) {
    const float* x = (const float*)d_in[0];
    const int* edge_src = (const int*)d_in[1];
    const int* edge_dst = (const int*)d_in[2];
    const float* edge_weight = (const float*)d_in[3];
    const float* W1 = (const float*)d_in[4];
    const float* b1 = (const float*)d_in[5];
    const float* Wh = (const float*)d_in[6];
    const float* bh = (const float*)d_in[7];
    const float* W2 = (const float*)d_in[8];
    const float* b2 = (const float*)d_in[9];
    float* out = (float*)d_out;

    size_t off = 0;
    auto carve = [&](size_t bytes) {
        void* p = (char*)d_ws + off;
        off += (bytes + 511) & ~(size_t)511;
        return p;
    };
    unsigned short* tb = (unsigned short*)carve((size_t)N_NODES * 128 * 2);
    unsigned short* hb = (unsigned short*)carve((size_t)N_NODES * 128 * 2);
    unsigned short* t3 = (unsigned short*)carve((size_t)N_NODES * NCLASS * 2);
    unsigned short* Wt1 = (unsigned short*)carve((size_t)NFEAT * NHID * 2);
    unsigned short* Wth = (unsigned short*)carve((size_t)NHID * NHID * 2);
    int* row_ptr = (int*)carve((size_t)(N_NODES + 4) * 4);
    int* bucketCursor = (int*)carve((size_t)NBUCKETS * 4);
    int* bucketStart = (int*)carve((size_t)(NBUCKETS + 1) * 4);
    uint2* binned = (uint2*)carve((size_t)NBUCKETS * BUCKET_CAP * 8);
    unsigned int* pairs = (unsigned int*)carve((size_t)N_EDGES * 4);
    (void)ws_size; (void)n_in; (void)in_sizes; (void)out_size;

    const int binBlocks = (N_EDGES + 4095) / 4096;     // 391
    const int spmmBlocks = N_NODES / 4;                // 12500
    const int tileBlocks = (N_NODES + 127) / 128;      // 391
    const int gemmBlocks = (N_NODES + 63) / 64;        // 782

    // CSR build (two-pass binning)
    zero_cursors<<<1, 256, 0, stream>>>(bucketCursor);
    bin_kernel<<<binBlocks, 256, 0, stream>>>(edge_src, edge_dst, edge_weight,
                                              bucketCursor, binned, N_EDGES);
    scan_buckets<<<1, 256, 0, stream>>>(bucketCursor, bucketStart);
    build_csr<<<NBUCKETS, 256, 0, stream>>>(binned, bucketStart, pairs, row_ptr);

    // weight prep
    transpose_to_bf16<<<(NFEAT * NHID + 255) / 256, 256, 0, stream>>>(W1, Wt1, NFEAT, NHID);
    transpose_to_bf16<<<(NHID * NHID + 255) / 256, 256, 0, stream>>>(Wh, Wth, NHID, NHID);

    // Layer 1
    gemm_tile_n128<false><<<tileBlocks, 256, 0, stream>>>(x, Wt1, tb, N_NODES, NFEAT);
    spmm_bias_relu_bf16<<<spmmBlocks, 256, 0, stream>>>(tb, row_ptr, pairs, b1, hb);

    // Layer 2
    gemm_tile_n128<true><<<tileBlocks, 256, 0, stream>>>(hb, Wth, tb, N_NODES, NHID);
    spmm_bias_relu_bf16<<<spmmBlocks, 256, 0, stream>>>(tb, row_ptr, pairs, bh, hb);

    // Layer 3
    gemm_n40_bf16A<<<gemmBlocks, 256, 0, stream>>>(hb, W2, t3, N_NODES);
    spmm_logsoftmax<<<spmmBlocks, 256, 0, stream>>>(t3, row_ptr, pairs, b2, out);
}